// Round 3
// baseline (1926.756 us; speedup 1.0000x reference)
//
#include <hip/hip_runtime.h>
#include <hip/hip_bf16.h>
#include <math.h>

#define N_PTS 262144
#define SBLOCKS 1024   // stats blocks

// ---------- helpers ----------
__device__ __forceinline__ int encf(float f) {
    int b = __float_as_int(f);
    return b >= 0 ? b : (b ^ 0x7fffffff);
}
__device__ __forceinline__ float decf(int b) {
    return __int_as_float(b >= 0 ? b : (b ^ 0x7fffffff));
}

// ---------- grouping ----------
__global__ void k_keys(const int* __restrict__ pt_ind, int* __restrict__ key, int* __restrict__ cnt) {
    int i = blockIdx.x * 256 + threadIdx.x;
    int b = pt_ind[i * 4 + 0], x = pt_ind[i * 4 + 1], y = pt_ind[i * 4 + 2], z = pt_ind[i * 4 + 3];
    int k = ((b * 64 + x) * 64 + y) * 16 + z;
    key[i] = k;
    atomicAdd(&cnt[k], 1);
}

// two-quantity scan: occupancy (cnt>0) -> rank, cnt -> start
__global__ __launch_bounds__(1024) void k_scan1(const int* __restrict__ cnt, int* __restrict__ rank,
                                                int* __restrict__ startb, int2* __restrict__ bsums) {
    __shared__ int so[1024], sc[1024];
    int t = threadIdx.x;
    int g = blockIdx.x * 1024 + t;
    int c = cnt[g];
    int o = (c > 0) ? 1 : 0;
    so[t] = o; sc[t] = c;
    __syncthreads();
    for (int off = 1; off < 1024; off <<= 1) {
        int vo = (t >= off) ? so[t - off] : 0;
        int vc = (t >= off) ? sc[t - off] : 0;
        __syncthreads();
        if (t >= off) { so[t] += vo; sc[t] += vc; }
        __syncthreads();
    }
    rank[g] = so[t] - o;       // exclusive
    startb[g] = sc[t] - c;     // exclusive
    if (t == 1023) bsums[blockIdx.x] = make_int2(so[t], sc[t]);
}

__global__ void k_scan2(int2* __restrict__ bsums, int* __restrict__ devU) {
    __shared__ int so[256], sc[256];
    int t = threadIdx.x;
    int2 v = bsums[t];
    so[t] = v.x; sc[t] = v.y;
    __syncthreads();
    for (int off = 1; off < 256; off <<= 1) {
        int vo = (t >= off) ? so[t - off] : 0;
        int vc = (t >= off) ? sc[t - off] : 0;
        __syncthreads();
        if (t >= off) { so[t] += vo; sc[t] += vc; }
        __syncthreads();
    }
    bsums[t] = make_int2(so[t] - v.x, sc[t] - v.y);  // exclusive block offsets
    if (t == 255) *devU = so[255];                    // total unique count
}

__global__ __launch_bounds__(1024) void k_scan3(int* __restrict__ rank, int* __restrict__ startb,
                                                const int2* __restrict__ bsums) {
    int g = blockIdx.x * 1024 + threadIdx.x;
    int2 o = bsums[blockIdx.x];
    rank[g] += o.x;
    startb[g] += o.y;
}

__global__ void k_scatter(const int* __restrict__ key, const int* __restrict__ rank,
                          const int* __restrict__ startb, int* __restrict__ cursor,
                          int* __restrict__ bucket, int* __restrict__ unq_inv) {
    int i = blockIdx.x * 256 + threadIdx.x;
    int k = key[i];
    unq_inv[i] = rank[k];
    int pos = startb[k] + atomicAdd(&cursor[k], 1);
    bucket[pos] = i;
}

__global__ void k_grouprank(const int* __restrict__ key, const int* __restrict__ cnt,
                            const int* __restrict__ startb, const int* __restrict__ bucket,
                            int* __restrict__ maskb, int* __restrict__ n_masked) {
    int i = blockIdx.x * 256 + threadIdx.x;
    int k = key[i];
    int s = startb[k];
    int c = cnt[k];
    int g = 0;
    for (int j = 0; j < c; j++) {
        int p = bucket[s + j];
        g += (p < i) ? 1 : 0;
    }
    int m = (g < 64) ? 1 : 0;
    maskb[i] = m;
    unsigned long long bal = __ballot(m);
    if ((threadIdx.x & 63) == 0) atomicAdd(n_masked, (int)__popcll(bal));
}

__global__ void k_coords(const int* __restrict__ cnt, const int* __restrict__ rank,
                         const int* __restrict__ devU, float* __restrict__ out) {
    int k = blockIdx.x * 256 + threadIdx.x;
    int U = *devU;
    if (cnt[k] > 0) {
        int r = rank[k];
        int z = k & 15;
        int t = k >> 4;
        int y = t & 63; t >>= 6;
        int x = t & 63;
        int b = t >> 6;
        out[r * 4 + 0] = (float)b;
        out[r * 4 + 1] = (float)x;
        out[r * 4 + 2] = (float)y;
        out[r * 4 + 3] = (float)z;
    }
    if (k >= U) {
        out[k * 4 + 0] = -1.f;
        out[k * 4 + 1] = -1.f;
        out[k * 4 + 2] = -1.f;
        out[k * 4 + 3] = -1.f;
    }
}

// ---------- masked BN stats ----------
template<int F, int FP>
__global__ __launch_bounds__(256) void k_stats(const float* __restrict__ buf, const int* __restrict__ maskb,
                                               float* __restrict__ psum, float* __restrict__ psq) {
    constexpr int RG = 256 / FP;
    int tid = threadIdx.x;
    int col = tid % FP;
    int rg = tid / FP;
    constexpr int RPB = N_PTS / SBLOCKS;  // 256 rows per block
    int r0 = blockIdx.x * RPB;
    float s = 0.f, q = 0.f;
    for (int r = r0 + rg; r < r0 + RPB; r += RG) {
        float mf = (float)maskb[r];
        if (col < F) {
            float v = buf[(size_t)r * F + col];
            s += v * mf;
            q += v * v * mf;
        }
    }
    __shared__ float ls[256], lq[256];
    ls[tid] = s; lq[tid] = q;
    __syncthreads();
    for (int half = RG / 2; half > 0; half >>= 1) {
        if (rg < half) { ls[tid] += ls[tid + half * FP]; lq[tid] += lq[tid + half * FP]; }
        __syncthreads();
    }
    if (rg == 0 && col < F) {
        psum[blockIdx.x * F + col] = ls[tid];
        psq[blockIdx.x * F + col] = lq[tid];
    }
}

// one block per feature column; 256 threads tree-reduce SBLOCKS partials in double
template<int F>
__global__ __launch_bounds__(256) void k_finalize(const float* __restrict__ psum, const float* __restrict__ psq,
                                                  const int* __restrict__ n_masked, const float* __restrict__ g,
                                                  const float* __restrict__ b, float* __restrict__ ss) {
    int j = blockIdx.x;
    int t = threadIdx.x;
    double s = 0.0, q = 0.0;
    for (int i = t; i < SBLOCKS; i += 256) {
        s += (double)psum[i * F + j];
        q += (double)psq[i * F + j];
    }
    __shared__ double ds[256], dq[256];
    ds[t] = s; dq[t] = q;
    __syncthreads();
    for (int half = 128; half > 0; half >>= 1) {
        if (t < half) { ds[t] += ds[t + half]; dq[t] += dq[t + half]; }
        __syncthreads();
    }
    if (t == 0) {
        double n = (double)(*n_masked);
        double mean = ds[0] / n;
        double var = dq[0] / n - mean * mean;
        if (var < 0.0) var = 0.0;
        double scale = (double)g[j] / sqrt(var + 1e-5);
        ss[j * 2] = (float)scale;
        ss[j * 2 + 1] = (float)((double)b[j] - mean * scale);
    }
}

// ---------- pooled init ----------
__global__ void k_fill(int4* __restrict__ p, int v, int n4) {
    int i = blockIdx.x * 256 + threadIdx.x;
    if (i < n4) p[i] = make_int4(v, v, v, v);
}

// ---------- GEMM ----------
// MODE 0: write pre-BN activation buffer
// MODE 1: pooled atomicMax epilogue (masked rows only)
// MODE 2: A = encoded pooled ints (decode, zero rows >= U), relu(acc+bias) -> out
template<int K, int F, int TM, int TN, int MODE, bool RELU, bool HAS_SS>
__global__ __launch_bounds__(256) void k_mm(const void* __restrict__ Ap, const float* __restrict__ W,
                                            const float* __restrict__ bias, const float* __restrict__ ss,
                                            const int* __restrict__ maskb, const int* __restrict__ unq_inv,
                                            const int* __restrict__ devU,
                                            float* __restrict__ out, int* __restrict__ pooled) {
    constexpr int SLOTS = F / TN;
    constexpr int RG = 256 / SLOTS;
    constexpr int MT = TM * RG;         // 64 rows per block
    constexpr int STRIDE = (K == 256) ? 256 : ((K == 9) ? 12 : K + 4);
    __shared__ float As[MT * STRIDE];

    int tid = threadIdx.x;
    int row0 = blockIdx.x * MT;

    // ---- stage A tile (with fused BN normalize / relu / decode) ----
    if constexpr (MODE == 2) {
        const int* Ai = (const int*)Ap;
        int U = *devU;
        for (int idx = tid; idx < MT * K / 4; idx += 256) {
            int r = idx / (K / 4);
            int k4 = (idx % (K / 4)) * 4;
            int4 e = *(const int4*)(Ai + (size_t)(row0 + r) * K + k4);
            bool valid = (row0 + r) < U;
            As[r * STRIDE + k4 + 0] = valid ? decf(e.x) : 0.f;
            As[r * STRIDE + k4 + 1] = valid ? decf(e.y) : 0.f;
            As[r * STRIDE + k4 + 2] = valid ? decf(e.z) : 0.f;
            As[r * STRIDE + k4 + 3] = valid ? decf(e.w) : 0.f;
        }
    } else if constexpr ((K % 4) == 0) {
        const float* Af = (const float*)Ap;
        for (int idx = tid; idx < MT * K / 4; idx += 256) {
            int r = idx / (K / 4);
            int k4 = (idx % (K / 4)) * 4;
            float4 x = *(const float4*)(Af + (size_t)(row0 + r) * K + k4);
            float vv[4] = {x.x, x.y, x.z, x.w};
            #pragma unroll
            for (int j = 0; j < 4; j++) {
                float v = vv[j];
                if constexpr (HAS_SS) v = v * ss[(k4 + j) * 2] + ss[(k4 + j) * 2 + 1];
                if constexpr (RELU) v = fmaxf(v, 0.f);
                As[r * STRIDE + k4 + j] = v;
            }
        }
    } else {
        const float* Af = (const float*)Ap;
        for (int idx = tid; idx < MT * K; idx += 256) {
            int r = idx / K;
            int kk = idx % K;
            float v = Af[(size_t)(row0 + r) * K + kk];
            if constexpr (HAS_SS) v = v * ss[kk * 2] + ss[kk * 2 + 1];
            if constexpr (RELU) v = fmaxf(v, 0.f);
            As[r * STRIDE + kk] = v;
        }
    }
    __syncthreads();

    int slot = tid % SLOTS;
    int rg = tid / SLOTS;

    float acc[TM][TN];
    #pragma unroll
    for (int m = 0; m < TM; m++)
        #pragma unroll
        for (int i = 0; i < TN; i++) acc[m][i] = 0.f;

    if constexpr ((K % 4) == 0) {
        // 4-deep k unroll, A-tile consumed via float4 (ds_read_b128, broadcast per half-wave)
        for (int k = 0; k < K; k += 4) {
            float4 a4[TM];
            #pragma unroll
            for (int m = 0; m < TM; m++)
                a4[m] = *(const float4*)&As[(rg * TM + m) * STRIDE + k];
            #pragma unroll
            for (int kk = 0; kk < 4; kk++) {
                float w[TN];
                #pragma unroll
                for (int i = 0; i < TN; i++) w[i] = W[(k + kk) * F + slot + i * SLOTS];
                #pragma unroll
                for (int m = 0; m < TM; m++) {
                    float a = (&a4[m].x)[kk];
                    #pragma unroll
                    for (int i = 0; i < TN; i++) acc[m][i] = fmaf(a, w[i], acc[m][i]);
                }
            }
        }
    } else {
        #pragma unroll 3
        for (int k = 0; k < K; k++) {
            float w[TN];
            #pragma unroll
            for (int i = 0; i < TN; i++) w[i] = W[k * F + slot + i * SLOTS];
            #pragma unroll
            for (int m = 0; m < TM; m++) {
                float a = As[(rg * TM + m) * STRIDE + k];
                #pragma unroll
                for (int i = 0; i < TN; i++) acc[m][i] = fmaf(a, w[i], acc[m][i]);
            }
        }
    }

    // ---- epilogue ----
    #pragma unroll
    for (int m = 0; m < TM; m++) {
        int r = row0 + rg * TM + m;
        if constexpr (MODE == 0) {
            #pragma unroll
            for (int i = 0; i < TN; i++) {
                int c = slot + i * SLOTS;
                out[(size_t)r * F + c] = acc[m][i] + bias[c];
            }
        } else if constexpr (MODE == 1) {
            if (maskb[r]) {
                int g = unq_inv[r];
                #pragma unroll
                for (int i = 0; i < TN; i++) {
                    int c = slot + i * SLOTS;
                    atomicMax(&pooled[(size_t)g * F + c], encf(acc[m][i] + bias[c]));
                }
            }
        } else {
            #pragma unroll
            for (int i = 0; i < TN; i++) {
                int c = slot + i * SLOTS;
                out[(size_t)r * F + c] = fmaxf(acc[m][i] + bias[c], 0.f);
            }
        }
    }
}

extern "C" void kernel_launch(void* const* d_in, const int* in_sizes, int n_in,
                              void* d_out, int out_size, void* d_ws, size_t ws_size,
                              hipStream_t stream) {
    const float* pt_fea = (const float*)d_in[0];
    const int*   pt_ind = (const int*)d_in[1];
    const float* bn0_g = (const float*)d_in[2];
    const float* bn0_b = (const float*)d_in[3];
    const float* w1 = (const float*)d_in[4];
    const float* b1 = (const float*)d_in[5];
    const float* bn1_g = (const float*)d_in[6];
    const float* bn1_b = (const float*)d_in[7];
    const float* w2 = (const float*)d_in[8];
    const float* b2 = (const float*)d_in[9];
    const float* bn2_g = (const float*)d_in[10];
    const float* bn2_b = (const float*)d_in[11];
    const float* w3 = (const float*)d_in[12];
    const float* b3 = (const float*)d_in[13];
    const float* bn3_g = (const float*)d_in[14];
    const float* bn3_b = (const float*)d_in[15];
    const float* w4 = (const float*)d_in[16];
    const float* b4 = (const float*)d_in[17];
    const float* wc = (const float*)d_in[18];
    const float* bc = (const float*)d_in[19];

    float* outF = (float*)d_out;
    float* coords_out = outF;                       // N x 4
    float* feat_out = outF + (size_t)4 * N_PTS;     // N x 128

    char* wp = (char*)d_ws;
    auto alloc = [&](size_t bytes) {
        char* p = wp;
        wp += (bytes + 255) & ~(size_t)255;
        return p;
    };
    float* bufA = (float*)alloc((size_t)N_PTS * 256 * 4);
    float* bufB = (float*)alloc((size_t)N_PTS * 256 * 4);
    int* key     = (int*)alloc((size_t)N_PTS * 4);
    int* cnt     = (int*)alloc((size_t)N_PTS * 4);
    int* rank    = (int*)alloc((size_t)N_PTS * 4);
    int* startb  = (int*)alloc((size_t)N_PTS * 4);
    int* cursor  = (int*)alloc((size_t)N_PTS * 4);
    int* bucket  = (int*)alloc((size_t)N_PTS * 4);
    int* unq_inv = (int*)alloc((size_t)N_PTS * 4);
    int* maskb   = (int*)alloc((size_t)N_PTS * 4);
    int2* bsums  = (int2*)alloc(256 * sizeof(int2));
    int* devU    = (int*)alloc(256);
    int* n_masked= (int*)alloc(256);
    float* psum  = (float*)alloc((size_t)SBLOCKS * 256 * 4);
    float* psq   = (float*)alloc((size_t)SBLOCKS * 256 * 4);
    float* ss0   = (float*)alloc(2048);
    float* ss1   = (float*)alloc(2048);
    float* ss2   = (float*)alloc(2048);
    float* ss3   = (float*)alloc(2048);

    hipMemsetAsync(cnt, 0, (size_t)N_PTS * 4, stream);
    hipMemsetAsync(cursor, 0, (size_t)N_PTS * 4, stream);
    hipMemsetAsync(n_masked, 0, 4, stream);

    // grouping
    k_keys<<<N_PTS / 256, 256, 0, stream>>>(pt_ind, key, cnt);
    k_scan1<<<N_PTS / 1024, 1024, 0, stream>>>(cnt, rank, startb, bsums);
    k_scan2<<<1, 256, 0, stream>>>(bsums, devU);
    k_scan3<<<N_PTS / 1024, 1024, 0, stream>>>(rank, startb, bsums);
    k_scatter<<<N_PTS / 256, 256, 0, stream>>>(key, rank, startb, cursor, bucket, unq_inv);
    k_grouprank<<<N_PTS / 256, 256, 0, stream>>>(key, cnt, startb, bucket, maskb, n_masked);
    k_coords<<<N_PTS / 256, 256, 0, stream>>>(cnt, rank, devU, coords_out);

    // BN0 stats on pt_fea
    k_stats<9, 16><<<SBLOCKS, 256, 0, stream>>>(pt_fea, maskb, psum, psq);
    k_finalize<9><<<9, 256, 0, stream>>>(psum, psq, n_masked, bn0_g, bn0_b, ss0);

    // L1: (bn0(pt_fea)) @ w1 + b1 -> bufA (N x 64)
    k_mm<9, 64, 4, 4, 0, false, true><<<N_PTS / 64, 256, 0, stream>>>(
        pt_fea, w1, b1, ss0, nullptr, nullptr, nullptr, bufA, nullptr);
    k_stats<64, 64><<<SBLOCKS, 256, 0, stream>>>(bufA, maskb, psum, psq);
    k_finalize<64><<<64, 256, 0, stream>>>(psum, psq, n_masked, bn1_g, bn1_b, ss1);

    // L2: relu(bn1(bufA)) @ w2 + b2 -> bufB (N x 128)
    k_mm<64, 128, 4, 8, 0, true, true><<<N_PTS / 64, 256, 0, stream>>>(
        bufA, w2, b2, ss1, nullptr, nullptr, nullptr, bufB, nullptr);
    k_stats<128, 128><<<SBLOCKS, 256, 0, stream>>>(bufB, maskb, psum, psq);
    k_finalize<128><<<128, 256, 0, stream>>>(psum, psq, n_masked, bn2_g, bn2_b, ss2);

    // L3: relu(bn2(bufB)) @ w3 + b3 -> bufA (N x 256)
    k_mm<128, 256, 8, 8, 0, true, true><<<N_PTS / 64, 256, 0, stream>>>(
        bufB, w3, b3, ss2, nullptr, nullptr, nullptr, bufA, nullptr);
    k_stats<256, 256><<<SBLOCKS, 256, 0, stream>>>(bufA, maskb, psum, psq);
    k_finalize<256><<<256, 256, 0, stream>>>(psum, psq, n_masked, bn3_g, bn3_b, ss3);

    // pooled init to enc(-inf), then L4 + masked segment-max into bufB (as int)
    k_fill<<<(N_PTS * 256 / 4 + 255) / 256, 256, 0, stream>>>((int4*)bufB, 0x807fffff, N_PTS * 256 / 4);
    k_mm<256, 256, 8, 8, 1, true, true><<<N_PTS / 64, 256, 0, stream>>>(
        bufA, w4, b4, ss3, maskb, unq_inv, nullptr, nullptr, (int*)bufB);

    // final: relu(pooled @ wc + bc) -> feat_out
    k_mm<256, 128, 4, 8, 2, false, false><<<N_PTS / 64, 256, 0, stream>>>(
        bufB, wc, bc, nullptr, nullptr, nullptr, devU, feat_out, nullptr);
}

// Round 5
// 1373.349 us; speedup vs baseline: 1.4030x; 1.4030x over previous
//
#include <hip/hip_runtime.h>
#include <hip/hip_bf16.h>
#include <math.h>

#define N_PTS 262144
#define SBLOCKS 1024   // stats blocks

typedef short short8 __attribute__((ext_vector_type(8)));
typedef float f32x4 __attribute__((ext_vector_type(4)));

// ---------- helpers ----------
__device__ __forceinline__ int encf(float f) {
    int b = __float_as_int(f);
    return b >= 0 ? b : (b ^ 0x7fffffff);
}
__device__ __forceinline__ float decf(int b) {
    return __int_as_float(b >= 0 ? b : (b ^ 0x7fffffff));
}
__device__ __forceinline__ unsigned short f2bf(float f) {  // RNE
    unsigned u = __float_as_uint(f);
    u = u + 0x7fff + ((u >> 16) & 1);
    return (unsigned short)(u >> 16);
}
__device__ __forceinline__ float bf2f(unsigned short h) {
    return __uint_as_float(((unsigned)h) << 16);
}

// ---------- grouping ----------
__global__ void k_keys(const int* __restrict__ pt_ind, int* __restrict__ key, int* __restrict__ cnt) {
    int i = blockIdx.x * 256 + threadIdx.x;
    int b = pt_ind[i * 4 + 0], x = pt_ind[i * 4 + 1], y = pt_ind[i * 4 + 2], z = pt_ind[i * 4 + 3];
    int k = ((b * 64 + x) * 64 + y) * 16 + z;
    key[i] = k;
    atomicAdd(&cnt[k], 1);
}

__global__ __launch_bounds__(1024) void k_scan1(const int* __restrict__ cnt, int* __restrict__ rank,
                                                int* __restrict__ startb, int2* __restrict__ bsums) {
    __shared__ int so[1024], sc[1024];
    int t = threadIdx.x;
    int g = blockIdx.x * 1024 + t;
    int c = cnt[g];
    int o = (c > 0) ? 1 : 0;
    so[t] = o; sc[t] = c;
    __syncthreads();
    for (int off = 1; off < 1024; off <<= 1) {
        int vo = (t >= off) ? so[t - off] : 0;
        int vc = (t >= off) ? sc[t - off] : 0;
        __syncthreads();
        if (t >= off) { so[t] += vo; sc[t] += vc; }
        __syncthreads();
    }
    rank[g] = so[t] - o;
    startb[g] = sc[t] - c;
    if (t == 1023) bsums[blockIdx.x] = make_int2(so[t], sc[t]);
}

__global__ void k_scan2(int2* __restrict__ bsums, int* __restrict__ devU) {
    __shared__ int so[256], sc[256];
    int t = threadIdx.x;
    int2 v = bsums[t];
    so[t] = v.x; sc[t] = v.y;
    __syncthreads();
    for (int off = 1; off < 256; off <<= 1) {
        int vo = (t >= off) ? so[t - off] : 0;
        int vc = (t >= off) ? sc[t - off] : 0;
        __syncthreads();
        if (t >= off) { so[t] += vo; sc[t] += vc; }
        __syncthreads();
    }
    bsums[t] = make_int2(so[t] - v.x, sc[t] - v.y);
    if (t == 255) *devU = so[255];
}

__global__ __launch_bounds__(1024) void k_scan3(int* __restrict__ rank, int* __restrict__ startb,
                                                const int2* __restrict__ bsums) {
    int g = blockIdx.x * 1024 + threadIdx.x;
    int2 o = bsums[blockIdx.x];
    rank[g] += o.x;
    startb[g] += o.y;
}

__global__ void k_scatter(const int* __restrict__ key, const int* __restrict__ rank,
                          const int* __restrict__ startb, int* __restrict__ cursor,
                          int* __restrict__ bucket, int* __restrict__ unq_inv) {
    int i = blockIdx.x * 256 + threadIdx.x;
    int k = key[i];
    unq_inv[i] = rank[k];
    int pos = startb[k] + atomicAdd(&cursor[k], 1);
    bucket[pos] = i;
}

__global__ void k_grouprank(const int* __restrict__ key, const int* __restrict__ cnt,
                            const int* __restrict__ startb, const int* __restrict__ bucket,
                            int* __restrict__ maskb, int* __restrict__ n_masked) {
    int i = blockIdx.x * 256 + threadIdx.x;
    int k = key[i];
    int s = startb[k];
    int c = cnt[k];
    int g = 0;
    for (int j = 0; j < c; j++) {
        int p = bucket[s + j];
        g += (p < i) ? 1 : 0;
    }
    int m = (g < 64) ? 1 : 0;
    maskb[i] = m;
    unsigned long long bal = __ballot(m);
    if ((threadIdx.x & 63) == 0) atomicAdd(n_masked, (int)__popcll(bal));
}

__global__ void k_coords(const int* __restrict__ cnt, const int* __restrict__ rank,
                         const int* __restrict__ devU, float* __restrict__ out) {
    int k = blockIdx.x * 256 + threadIdx.x;
    int U = *devU;
    if (cnt[k] > 0) {
        int r = rank[k];
        int z = k & 15;
        int t = k >> 4;
        int y = t & 63; t >>= 6;
        int x = t & 63;
        int b = t >> 6;
        out[r * 4 + 0] = (float)b;
        out[r * 4 + 1] = (float)x;
        out[r * 4 + 2] = (float)y;
        out[r * 4 + 3] = (float)z;
    }
    if (k >= U) {
        out[k * 4 + 0] = -1.f;
        out[k * 4 + 1] = -1.f;
        out[k * 4 + 2] = -1.f;
        out[k * 4 + 3] = -1.f;
    }
}

// ---------- masked BN stats ----------
template<int F, int FP>
__global__ __launch_bounds__(256) void k_stats(const float* __restrict__ buf, const int* __restrict__ maskb,
                                               float* __restrict__ psum, float* __restrict__ psq) {
    constexpr int RG = 256 / FP;
    int tid = threadIdx.x;
    int col = tid % FP;
    int rg = tid / FP;
    constexpr int RPB = N_PTS / SBLOCKS;
    int r0 = blockIdx.x * RPB;
    float s = 0.f, q = 0.f;
    for (int r = r0 + rg; r < r0 + RPB; r += RG) {
        float mf = (float)maskb[r];
        if (col < F) {
            float v = buf[(size_t)r * F + col];
            s += v * mf;
            q += v * v * mf;
        }
    }
    __shared__ float ls[256], lq[256];
    ls[tid] = s; lq[tid] = q;
    __syncthreads();
    for (int half = RG / 2; half > 0; half >>= 1) {
        if (rg < half) { ls[tid] += ls[tid + half * FP]; lq[tid] += lq[tid + half * FP]; }
        __syncthreads();
    }
    if (rg == 0 && col < F) {
        psum[blockIdx.x * F + col] = ls[tid];
        psq[blockIdx.x * F + col] = lq[tid];
    }
}

template<int F>
__global__ __launch_bounds__(256) void k_finalize(const float* __restrict__ psum, const float* __restrict__ psq,
                                                  const int* __restrict__ n_masked, const float* __restrict__ g,
                                                  const float* __restrict__ b, float* __restrict__ ss) {
    int j = blockIdx.x;
    int t = threadIdx.x;
    double s = 0.0, q = 0.0;
    for (int i = t; i < SBLOCKS; i += 256) {
        s += (double)psum[i * F + j];
        q += (double)psq[i * F + j];
    }
    __shared__ double ds[256], dq[256];
    ds[t] = s; dq[t] = q;
    __syncthreads();
    for (int half = 128; half > 0; half >>= 1) {
        if (t < half) { ds[t] += ds[t + half]; dq[t] += dq[t + half]; }
        __syncthreads();
    }
    if (t == 0) {
        double n = (double)(*n_masked);
        double mean = ds[0] / n;
        double var = dq[0] / n - mean * mean;
        if (var < 0.0) var = 0.0;
        double scale = (double)g[j] / sqrt(var + 1e-5);
        ss[j * 2] = (float)scale;
        ss[j * 2 + 1] = (float)((double)b[j] - mean * scale);
    }
}

// ---------- pooled init ----------
__global__ void k_fill(int4* __restrict__ p, int v, int n4) {
    int i = blockIdx.x * 256 + threadIdx.x;
    if (i < n4) p[i] = make_int4(v, v, v, v);
}

// ---------- W transpose + hi/lo bf16 split (once per launch, tiny) ----------
__global__ void k_wsplit(const float* __restrict__ W, int K, int F,
                         unsigned short* __restrict__ WtH, unsigned short* __restrict__ WtL) {
    int idx = blockIdx.x * 256 + threadIdx.x;
    if (idx >= K * F) return;
    int k = idx / F, f = idx % F;
    float v = W[idx];
    unsigned short h = f2bf(v);
    float lo = v - bf2f(h);
    WtH[f * K + k] = h;
    WtL[f * K + k] = f2bf(lo);
}

// ---------- fp32 vector GEMM (only for L1, K=9) ----------
template<int K, int F, int TM, int TN, int MODE, bool RELU, bool HAS_SS>
__global__ __launch_bounds__(256) void k_mm(const void* __restrict__ Ap, const float* __restrict__ W,
                                            const float* __restrict__ bias, const float* __restrict__ ss,
                                            const int* __restrict__ maskb, const int* __restrict__ unq_inv,
                                            const int* __restrict__ devU,
                                            float* __restrict__ out, int* __restrict__ pooled) {
    constexpr int SLOTS = F / TN;
    constexpr int RG = 256 / SLOTS;
    constexpr int MT = TM * RG;
    constexpr int STRIDE = (K == 256) ? 256 : ((K == 9) ? 12 : K + 4);
    __shared__ float As[MT * STRIDE];

    int tid = threadIdx.x;
    int row0 = blockIdx.x * MT;

    {
        const float* Af = (const float*)Ap;
        for (int idx = tid; idx < MT * K; idx += 256) {
            int r = idx / K;
            int kk = idx % K;
            float v = Af[(size_t)(row0 + r) * K + kk];
            if constexpr (HAS_SS) v = v * ss[kk * 2] + ss[kk * 2 + 1];
            if constexpr (RELU) v = fmaxf(v, 0.f);
            As[r * STRIDE + kk] = v;
        }
    }
    __syncthreads();

    int slot = tid % SLOTS;
    int rg = tid / SLOTS;

    float acc[TM][TN];
    #pragma unroll
    for (int m = 0; m < TM; m++)
        #pragma unroll
        for (int i = 0; i < TN; i++) acc[m][i] = 0.f;

    #pragma unroll 3
    for (int k = 0; k < K; k++) {
        float w[TN];
        #pragma unroll
        for (int i = 0; i < TN; i++) w[i] = W[k * F + slot + i * SLOTS];
        #pragma unroll
        for (int m = 0; m < TM; m++) {
            float a = As[(rg * TM + m) * STRIDE + k];
            #pragma unroll
            for (int i = 0; i < TN; i++) acc[m][i] = fmaf(a, w[i], acc[m][i]);
        }
    }

    #pragma unroll
    for (int m = 0; m < TM; m++) {
        int r = row0 + rg * TM + m;
        #pragma unroll
        for (int i = 0; i < TN; i++) {
            int c = slot + i * SLOTS;
            out[(size_t)r * F + c] = acc[m][i] + bias[c];
        }
    }
}

// ---------- MFMA GEMM with bf16 hi/lo 3-term split (~fp32 precision) ----------
// Block tile 128x128, 4 waves (2x2), wave tile 64x64 = 4x4 frags of 16x16x32.
// A staged from fp32 (fused BN scale/shift + optional relu, or MODE2 decode).
// W pre-split to bf16 WtH/WtL (F x K, row-major) by k_wsplit.
// MODE 0: out = acc + bias; MODE 1: atomicMax pooled (masked rows); MODE 2: relu(acc+bias) -> out
template<int K, int F, int MODE, bool RELU_IN, bool HAS_SS>
__global__ __launch_bounds__(256) void k_mfma(const void* __restrict__ Ap,
                                              const unsigned short* __restrict__ WtH,
                                              const unsigned short* __restrict__ WtL,
                                              const float* __restrict__ bias, const float* __restrict__ ss,
                                              const int* __restrict__ maskb, const int* __restrict__ unq_inv,
                                              const int* __restrict__ devU,
                                              float* __restrict__ out, int* __restrict__ pooled) {
    __shared__ unsigned short AsH[128 * 64], AsL[128 * 64], WsH[128 * 64], WsL[128 * 64];
    int tid = threadIdx.x;
    int row0 = blockIdx.x * 128;
    int c0 = blockIdx.y * 128;
    int w = tid >> 6, lane = tid & 63;
    int wm = w >> 1, wn = w & 1;
    int lr = lane & 15, lg = lane >> 4;

    f32x4 acc[4][4];
    #pragma unroll
    for (int m = 0; m < 4; m++)
        #pragma unroll
        for (int n = 0; n < 4; n++) acc[m][n] = (f32x4)(0.f);

    int U = 0;
    if constexpr (MODE == 2) U = *devU;

    for (int kc = 0; kc < K; kc += 64) {
        // ---- stage A (128 rows x 64 k) as bf16 hi/lo, swizzled ----
        #pragma unroll
        for (int it = 0; it < 8; ++it) {
            int idx = it * 256 + tid;
            int r = idx >> 4, p = idx & 15;
            int gk = kc + p * 4;
            float v[4];
            if constexpr (MODE == 2) {
                int4 e = *(const int4*)((const int*)Ap + (size_t)(row0 + r) * K + gk);
                bool valid = (row0 + r) < U;
                v[0] = valid ? decf(e.x) : 0.f;
                v[1] = valid ? decf(e.y) : 0.f;
                v[2] = valid ? decf(e.z) : 0.f;
                v[3] = valid ? decf(e.w) : 0.f;
            } else {
                float4 x = *(const float4*)((const float*)Ap + (size_t)(row0 + r) * K + gk);
                v[0] = x.x; v[1] = x.y; v[2] = x.z; v[3] = x.w;
                #pragma unroll
                for (int j = 0; j < 4; j++) {
                    if constexpr (HAS_SS) v[j] = v[j] * ss[(gk + j) * 2] + ss[(gk + j) * 2 + 1];
                    if constexpr (RELU_IN) v[j] = fmaxf(v[j], 0.f);
                }
            }
            ushort4 h, l;
            h.x = f2bf(v[0]); l.x = f2bf(v[0] - bf2f(h.x));
            h.y = f2bf(v[1]); l.y = f2bf(v[1] - bf2f(h.y));
            h.z = f2bf(v[2]); l.z = f2bf(v[2] - bf2f(h.z));
            h.w = f2bf(v[3]); l.w = f2bf(v[3] - bf2f(h.w));
            int us = (r * 64 + p * 4) ^ ((r & 7) << 3);
            *(ushort4*)&AsH[us] = h;
            *(ushort4*)&AsL[us] = l;
        }
        // ---- stage W^T (128 cols x 64 k) bf16 hi/lo, swizzled ----
        #pragma unroll
        for (int it = 0; it < 8; ++it) {
            int idx = it * 256 + tid;
            int c = idx >> 4, p = idx & 15;
            size_t g = (size_t)(c0 + c) * K + kc + p * 4;
            ushort4 h = *(const ushort4*)&WtH[g];
            ushort4 l = *(const ushort4*)&WtL[g];
            int us = (c * 64 + p * 4) ^ ((c & 7) << 3);
            *(ushort4*)&WsH[us] = h;
            *(ushort4*)&WsL[us] = l;
        }
        __syncthreads();

        #pragma unroll
        for (int kb = 0; kb < 2; ++kb) {
            short8 bh[4], bl[4];
            #pragma unroll
            for (int n = 0; n < 4; n++) {
                int c = wn * 64 + n * 16 + lr;
                int us = (c * 64 + kb * 32 + lg * 8) ^ ((c & 7) << 3);
                bh[n] = *(const short8*)&WsH[us];
                bl[n] = *(const short8*)&WsL[us];
            }
            #pragma unroll
            for (int m = 0; m < 4; m++) {
                int r = wm * 64 + m * 16 + lr;
                int us = (r * 64 + kb * 32 + lg * 8) ^ ((r & 7) << 3);
                short8 ah = *(const short8*)&AsH[us];
                short8 al = *(const short8*)&AsL[us];
                #pragma unroll
                for (int n = 0; n < 4; n++) {
                    acc[m][n] = __builtin_amdgcn_mfma_f32_16x16x32_bf16(ah, bh[n], acc[m][n], 0, 0, 0);
                    acc[m][n] = __builtin_amdgcn_mfma_f32_16x16x32_bf16(ah, bl[n], acc[m][n], 0, 0, 0);
                    acc[m][n] = __builtin_amdgcn_mfma_f32_16x16x32_bf16(al, bh[n], acc[m][n], 0, 0, 0);
                }
            }
        }
        __syncthreads();
    }

    // ---- epilogue ----
    float bn[4];
    #pragma unroll
    for (int n = 0; n < 4; n++) bn[n] = bias[c0 + wn * 64 + n * 16 + lr];

    if constexpr (MODE == 1) {
        #pragma unroll
        for (int m = 0; m < 4; m++) {
            #pragma unroll
            for (int reg = 0; reg < 4; reg++) {
                int row = row0 + wm * 64 + m * 16 + lg * 4 + reg;
                if (maskb[row]) {
                    int g = unq_inv[row];
                    #pragma unroll
                    for (int n = 0; n < 4; n++) {
                        int col = c0 + wn * 64 + n * 16 + lr;
                        atomicMax(&pooled[(size_t)g * F + col], encf(acc[m][n][reg] + bn[n]));
                    }
                }
            }
        }
    } else {
        #pragma unroll
        for (int m = 0; m < 4; m++) {
            #pragma unroll
            for (int n = 0; n < 4; n++) {
                int col = c0 + wn * 64 + n * 16 + lr;
                #pragma unroll
                for (int reg = 0; reg < 4; reg++) {
                    int row = row0 + wm * 64 + m * 16 + lg * 4 + reg;
                    float v = acc[m][n][reg] + bn[n];
                    if constexpr (MODE == 2) v = fmaxf(v, 0.f);
                    out[(size_t)row * F + col] = v;
                }
            }
        }
    }
}

extern "C" void kernel_launch(void* const* d_in, const int* in_sizes, int n_in,
                              void* d_out, int out_size, void* d_ws, size_t ws_size,
                              hipStream_t stream) {
    const float* pt_fea = (const float*)d_in[0];
    const int*   pt_ind = (const int*)d_in[1];
    const float* bn0_g = (const float*)d_in[2];
    const float* bn0_b = (const float*)d_in[3];
    const float* w1 = (const float*)d_in[4];
    const float* b1 = (const float*)d_in[5];
    const float* bn1_g = (const float*)d_in[6];
    const float* bn1_b = (const float*)d_in[7];
    const float* w2 = (const float*)d_in[8];
    const float* b2 = (const float*)d_in[9];
    const float* bn2_g = (const float*)d_in[10];
    const float* bn2_b = (const float*)d_in[11];
    const float* w3 = (const float*)d_in[12];
    const float* b3 = (const float*)d_in[13];
    const float* bn3_g = (const float*)d_in[14];
    const float* bn3_b = (const float*)d_in[15];
    const float* w4 = (const float*)d_in[16];
    const float* b4 = (const float*)d_in[17];
    const float* wc = (const float*)d_in[18];
    const float* bc = (const float*)d_in[19];

    float* outF = (float*)d_out;
    float* coords_out = outF;
    float* feat_out = outF + (size_t)4 * N_PTS;

    char* wp = (char*)d_ws;
    auto alloc = [&](size_t bytes) {
        char* p = wp;
        wp += (bytes + 255) & ~(size_t)255;
        return p;
    };
    float* bufA = (float*)alloc((size_t)N_PTS * 256 * 4);
    float* bufB = (float*)alloc((size_t)N_PTS * 256 * 4);
    int* key     = (int*)alloc((size_t)N_PTS * 4);
    int* cnt     = (int*)alloc((size_t)N_PTS * 4);
    int* rank    = (int*)alloc((size_t)N_PTS * 4);
    int* startb  = (int*)alloc((size_t)N_PTS * 4);
    int* cursor  = (int*)alloc((size_t)N_PTS * 4);
    int* bucket  = (int*)alloc((size_t)N_PTS * 4);
    int* unq_inv = (int*)alloc((size_t)N_PTS * 4);
    int* maskb   = (int*)alloc((size_t)N_PTS * 4);
    int2* bsums  = (int2*)alloc(256 * sizeof(int2));
    int* devU    = (int*)alloc(256);
    int* n_masked= (int*)alloc(256);
    float* psum  = (float*)alloc((size_t)SBLOCKS * 256 * 4);
    float* psq   = (float*)alloc((size_t)SBLOCKS * 256 * 4);
    float* ss0   = (float*)alloc(2048);
    float* ss1   = (float*)alloc(2048);
    float* ss2   = (float*)alloc(2048);
    float* ss3   = (float*)alloc(2048);
    unsigned short* wt2h = (unsigned short*)alloc(64 * 128 * 2);
    unsigned short* wt2l = (unsigned short*)alloc(64 * 128 * 2);
    unsigned short* wt3h = (unsigned short*)alloc(128 * 256 * 2);
    unsigned short* wt3l = (unsigned short*)alloc(128 * 256 * 2);
    unsigned short* wt4h = (unsigned short*)alloc(256 * 256 * 2);
    unsigned short* wt4l = (unsigned short*)alloc(256 * 256 * 2);
    unsigned short* wtch = (unsigned short*)alloc(256 * 128 * 2);
    unsigned short* wtcl = (unsigned short*)alloc(256 * 128 * 2);

    hipMemsetAsync(cnt, 0, (size_t)N_PTS * 4, stream);
    hipMemsetAsync(cursor, 0, (size_t)N_PTS * 4, stream);
    hipMemsetAsync(n_masked, 0, 4, stream);

    // W split/transpose (tiny)
    k_wsplit<<<(64 * 128 + 255) / 256, 256, 0, stream>>>(w2, 64, 128, wt2h, wt2l);
    k_wsplit<<<(128 * 256 + 255) / 256, 256, 0, stream>>>(w3, 128, 256, wt3h, wt3l);
    k_wsplit<<<(256 * 256 + 255) / 256, 256, 0, stream>>>(w4, 256, 256, wt4h, wt4l);
    k_wsplit<<<(256 * 128 + 255) / 256, 256, 0, stream>>>(wc, 256, 128, wtch, wtcl);

    // grouping
    k_keys<<<N_PTS / 256, 256, 0, stream>>>(pt_ind, key, cnt);
    k_scan1<<<N_PTS / 1024, 1024, 0, stream>>>(cnt, rank, startb, bsums);
    k_scan2<<<1, 256, 0, stream>>>(bsums, devU);
    k_scan3<<<N_PTS / 1024, 1024, 0, stream>>>(rank, startb, bsums);
    k_scatter<<<N_PTS / 256, 256, 0, stream>>>(key, rank, startb, cursor, bucket, unq_inv);
    k_grouprank<<<N_PTS / 256, 256, 0, stream>>>(key, cnt, startb, bucket, maskb, n_masked);
    k_coords<<<N_PTS / 256, 256, 0, stream>>>(cnt, rank, devU, coords_out);

    // BN0 stats on pt_fea
    k_stats<9, 16><<<SBLOCKS, 256, 0, stream>>>(pt_fea, maskb, psum, psq);
    k_finalize<9><<<9, 256, 0, stream>>>(psum, psq, n_masked, bn0_g, bn0_b, ss0);

    // L1: (bn0(pt_fea)) @ w1 + b1 -> bufA (N x 64)   [fp32 vector, K=9]
    k_mm<9, 64, 4, 4, 0, false, true><<<N_PTS / 64, 256, 0, stream>>>(
        pt_fea, w1, b1, ss0, nullptr, nullptr, nullptr, bufA, nullptr);
    k_stats<64, 64><<<SBLOCKS, 256, 0, stream>>>(bufA, maskb, psum, psq);
    k_finalize<64><<<64, 256, 0, stream>>>(psum, psq, n_masked, bn1_g, bn1_b, ss1);

    // L2: relu(bn1(bufA)) @ w2 + b2 -> bufB (N x 128)  [MFMA]
    k_mfma<64, 128, 0, true, true><<<dim3(N_PTS / 128, 1), 256, 0, stream>>>(
        bufA, wt2h, wt2l, b2, ss1, nullptr, nullptr, nullptr, bufB, nullptr);
    k_stats<128, 128><<<SBLOCKS, 256, 0, stream>>>(bufB, maskb, psum, psq);
    k_finalize<128><<<128, 256, 0, stream>>>(psum, psq, n_masked, bn2_g, bn2_b, ss2);

    // L3: relu(bn2(bufB)) @ w3 + b3 -> bufA (N x 256)  [MFMA]
    k_mfma<128, 256, 0, true, true><<<dim3(N_PTS / 128, 2), 256, 0, stream>>>(
        bufB, wt3h, wt3l, b3, ss2, nullptr, nullptr, nullptr, bufA, nullptr);
    k_stats<256, 256><<<SBLOCKS, 256, 0, stream>>>(bufA, maskb, psum, psq);
    k_finalize<256><<<256, 256, 0, stream>>>(psum, psq, n_masked, bn3_g, bn3_b, ss3);

    // pooled init to enc(-inf), then L4 + masked segment-max into bufB (as int)  [MFMA]
    k_fill<<<(N_PTS * 256 / 4 + 255) / 256, 256, 0, stream>>>((int4*)bufB, 0x807fffff, N_PTS * 256 / 4);
    k_mfma<256, 256, 1, true, true><<<dim3(N_PTS / 128, 2), 256, 0, stream>>>(
        bufA, wt4h, wt4l, b4, ss3, maskb, unq_inv, nullptr, nullptr, (int*)bufB);

    // final: relu(pooled @ wc + bc) -> feat_out  [MFMA, decode + zero invalid]
    k_mfma<256, 128, 2, false, false><<<dim3(N_PTS / 128, 1), 256, 0, stream>>>(
        bufB, wtch, wtcl, bc, nullptr, nullptr, nullptr, devU, feat_out, nullptr);
}

// Round 6
// 1356.489 us; speedup vs baseline: 1.4204x; 1.0124x over previous
//
#include <hip/hip_runtime.h>
#include <hip/hip_bf16.h>
#include <math.h>

#define N_PTS 262144
#define SBLOCKS 1024   // stats blocks

typedef short short8 __attribute__((ext_vector_type(8)));
typedef float f32x4 __attribute__((ext_vector_type(4)));

// ---------- helpers ----------
__device__ __forceinline__ unsigned short f2bf(float f) {  // RNE
    unsigned u = __float_as_uint(f);
    u = u + 0x7fff + ((u >> 16) & 1);
    return (unsigned short)(u >> 16);
}

// ---------- grouping ----------
__global__ void k_keys(const int* __restrict__ pt_ind, int* __restrict__ key, int* __restrict__ cnt) {
    int i = blockIdx.x * 256 + threadIdx.x;
    int b = pt_ind[i * 4 + 0], x = pt_ind[i * 4 + 1], y = pt_ind[i * 4 + 2], z = pt_ind[i * 4 + 3];
    int k = ((b * 64 + x) * 64 + y) * 16 + z;
    key[i] = k;
    atomicAdd(&cnt[k], 1);
}

__global__ __launch_bounds__(1024) void k_scan1(const int* __restrict__ cnt, int* __restrict__ rank,
                                                int* __restrict__ startb, int2* __restrict__ bsums) {
    __shared__ int so[1024], sc[1024];
    int t = threadIdx.x;
    int g = blockIdx.x * 1024 + t;
    int c = cnt[g];
    int o = (c > 0) ? 1 : 0;
    so[t] = o; sc[t] = c;
    __syncthreads();
    for (int off = 1; off < 1024; off <<= 1) {
        int vo = (t >= off) ? so[t - off] : 0;
        int vc = (t >= off) ? sc[t - off] : 0;
        __syncthreads();
        if (t >= off) { so[t] += vo; sc[t] += vc; }
        __syncthreads();
    }
    rank[g] = so[t] - o;
    startb[g] = sc[t] - c;
    if (t == 1023) bsums[blockIdx.x] = make_int2(so[t], sc[t]);
}

__global__ void k_scan2(int2* __restrict__ bsums, int* __restrict__ devU) {
    __shared__ int so[256], sc[256];
    int t = threadIdx.x;
    int2 v = bsums[t];
    so[t] = v.x; sc[t] = v.y;
    __syncthreads();
    for (int off = 1; off < 256; off <<= 1) {
        int vo = (t >= off) ? so[t - off] : 0;
        int vc = (t >= off) ? sc[t - off] : 0;
        __syncthreads();
        if (t >= off) { so[t] += vo; sc[t] += vc; }
        __syncthreads();
    }
    bsums[t] = make_int2(so[t] - v.x, sc[t] - v.y);
    if (t == 255) *devU = so[255];
}

__global__ __launch_bounds__(1024) void k_scan3(int* __restrict__ rank, int* __restrict__ startb,
                                                const int2* __restrict__ bsums) {
    int g = blockIdx.x * 1024 + threadIdx.x;
    int2 o = bsums[blockIdx.x];
    rank[g] += o.x;
    startb[g] += o.y;
}

__global__ void k_scatter(const int* __restrict__ key, const int* __restrict__ startb,
                          int* __restrict__ cursor, int* __restrict__ bucket) {
    int i = blockIdx.x * 256 + threadIdx.x;
    int k = key[i];
    int pos = startb[k] + atomicAdd(&cursor[k], 1);
    bucket[pos] = i;
}

// per sorted position: group-rank via original-index comparisons
__global__ void k_grouprank(const int* __restrict__ bucket, const int* __restrict__ key,
                            const int* __restrict__ cnt, const int* __restrict__ startb,
                            int* __restrict__ maskb_s, int* __restrict__ maskb_o,
                            int* __restrict__ n_masked) {
    int pos = blockIdx.x * 256 + threadIdx.x;
    int i = bucket[pos];
    int k = key[i];
    int s = startb[k];
    int c = cnt[k];
    int g = 0;
    for (int j = 0; j < c; j++) {
        int p = bucket[s + j];
        g += (p < i) ? 1 : 0;
    }
    int m = (g < 64) ? 1 : 0;
    maskb_s[pos] = m;
    maskb_o[i] = m;
    unsigned long long bal = __ballot(m);
    if ((threadIdx.x & 63) == 0) atomicAdd(n_masked, (int)__popcll(bal));
}

__global__ void k_coords(const int* __restrict__ cnt, const int* __restrict__ rank,
                         const int* __restrict__ startb, const int* __restrict__ devU,
                         float* __restrict__ out, int* __restrict__ ustart, int* __restrict__ ucnt) {
    int k = blockIdx.x * 256 + threadIdx.x;
    int U = *devU;
    if (cnt[k] > 0) {
        int r = rank[k];
        int z = k & 15;
        int t = k >> 4;
        int y = t & 63; t >>= 6;
        int x = t & 63;
        int b = t >> 6;
        out[r * 4 + 0] = (float)b;
        out[r * 4 + 1] = (float)x;
        out[r * 4 + 2] = (float)y;
        out[r * 4 + 3] = (float)z;
        ustart[r] = startb[k];
        ucnt[r] = cnt[k];
    }
    if (k >= U) {
        out[k * 4 + 0] = -1.f;
        out[k * 4 + 1] = -1.f;
        out[k * 4 + 2] = -1.f;
        out[k * 4 + 3] = -1.f;
    }
}

// ---------- masked BN stats ----------
template<int F, int FP>
__global__ __launch_bounds__(256) void k_stats(const float* __restrict__ buf, const int* __restrict__ maskb,
                                               float* __restrict__ psum, float* __restrict__ psq) {
    constexpr int RG = 256 / FP;
    int tid = threadIdx.x;
    int col = tid % FP;
    int rg = tid / FP;
    constexpr int RPB = N_PTS / SBLOCKS;
    int r0 = blockIdx.x * RPB;
    float s = 0.f, q = 0.f;
    for (int r = r0 + rg; r < r0 + RPB; r += RG) {
        float mf = (float)maskb[r];
        if (col < F) {
            float v = buf[(size_t)r * F + col];
            s += v * mf;
            q += v * v * mf;
        }
    }
    __shared__ float ls[256], lq[256];
    ls[tid] = s; lq[tid] = q;
    __syncthreads();
    for (int half = RG / 2; half > 0; half >>= 1) {
        if (rg < half) { ls[tid] += ls[tid + half * FP]; lq[tid] += lq[tid + half * FP]; }
        __syncthreads();
    }
    if (rg == 0 && col < F) {
        psum[blockIdx.x * F + col] = ls[tid];
        psq[blockIdx.x * F + col] = lq[tid];
    }
}

template<int F>
__global__ __launch_bounds__(256) void k_finalize(const float* __restrict__ psum, const float* __restrict__ psq,
                                                  const int* __restrict__ n_masked, const float* __restrict__ g,
                                                  const float* __restrict__ b, float* __restrict__ ss) {
    int j = blockIdx.x;
    int t = threadIdx.x;
    double s = 0.0, q = 0.0;
    for (int i = t; i < SBLOCKS; i += 256) {
        s += (double)psum[i * F + j];
        q += (double)psq[i * F + j];
    }
    __shared__ double ds[256], dq[256];
    ds[t] = s; dq[t] = q;
    __syncthreads();
    for (int half = 128; half > 0; half >>= 1) {
        if (t < half) { ds[t] += ds[t + half]; dq[t] += dq[t + half]; }
        __syncthreads();
    }
    if (t == 0) {
        double n = (double)(*n_masked);
        double mean = ds[0] / n;
        double var = dq[0] / n - mean * mean;
        if (var < 0.0) var = 0.0;
        double scale = (double)g[j] / sqrt(var + 1e-5);
        ss[j * 2] = (float)scale;
        ss[j * 2 + 1] = (float)((double)b[j] - mean * scale);
    }
}

// ---------- W prep: fold |s| into W, split to bf16 hi/lo; emit per-k (c0,c1) ----------
template<int K, int F>
__global__ void k_wprep(const float* __restrict__ W, const float* __restrict__ ss,
                        unsigned short* __restrict__ WH, unsigned short* __restrict__ WL,
                        float* __restrict__ c0a, float* __restrict__ c1a) {
    int idx = blockIdx.x * 256 + threadIdx.x;
    if (idx >= K * F) return;
    int k = idx / F, f = idx % F;
    float s = 1.f, t = 0.f;
    if (ss) { s = ss[k * 2]; t = ss[k * 2 + 1]; }
    float sg = (s >= 0.f) ? 1.f : -1.f;
    float as = fabsf(s);
    float c1, c0;
    if (as < 1e-30f) { c1 = 0.f; c0 = fmaxf(t, 0.f); as = 1.f; }
    else { c1 = sg; c0 = t / as; }
    if (f == 0) { c0a[k] = c0; c1a[k] = c1; }
    float wv = as * W[(size_t)k * F + f];
    unsigned u = __float_as_uint(wv);
    unsigned hk = u & 0xFFFF0000u;
    float lo = wv - __uint_as_float(hk);
    WH[(size_t)f * K + k] = (unsigned short)(hk >> 16);
    WL[(size_t)f * K + k] = f2bf(lo);
}

// ---------- fp32 vector GEMM for L1 (K=9), with row gather + BN0 ----------
__global__ __launch_bounds__(256) void k_mm1(const float* __restrict__ Af, const int* __restrict__ bucket,
                                             const float* __restrict__ W, const float* __restrict__ bias,
                                             const float* __restrict__ ss, float* __restrict__ out) {
    constexpr int K = 9, F = 64, TM = 4, TN = 4;
    constexpr int SLOTS = F / TN;      // 16
    constexpr int RG = 256 / SLOTS;    // 16
    constexpr int MT = TM * RG;        // 64
    constexpr int STRIDE = 12;
    __shared__ float As[MT * STRIDE];

    int tid = threadIdx.x;
    int row0 = blockIdx.x * MT;

    for (int idx = tid; idx < MT * K; idx += 256) {
        int r = idx / K;
        int kk = idx % K;
        int src = bucket[row0 + r];
        float v = Af[(size_t)src * K + kk];
        v = v * ss[kk * 2] + ss[kk * 2 + 1];
        As[r * STRIDE + kk] = v;
    }
    __syncthreads();

    int slot = tid % SLOTS;
    int rg = tid / SLOTS;

    float acc[TM][TN];
    #pragma unroll
    for (int m = 0; m < TM; m++)
        #pragma unroll
        for (int i = 0; i < TN; i++) acc[m][i] = 0.f;

    #pragma unroll 3
    for (int k = 0; k < K; k++) {
        float w[TN];
        #pragma unroll
        for (int i = 0; i < TN; i++) w[i] = W[k * F + slot + i * SLOTS];
        #pragma unroll
        for (int m = 0; m < TM; m++) {
            float a = As[(rg * TM + m) * STRIDE + k];
            #pragma unroll
            for (int i = 0; i < TN; i++) acc[m][i] = fmaf(a, w[i], acc[m][i]);
        }
    }

    #pragma unroll
    for (int m = 0; m < TM; m++) {
        int r = row0 + rg * TM + m;
        #pragma unroll
        for (int i = 0; i < TN; i++) {
            int c = slot + i * SLOTS;
            out[(size_t)r * F + c] = acc[m][i] + bias[c];
        }
    }
}

// ---------- MFMA GEMM: A in LDS (hi/lo, swizzled), W direct from global (L2-hot) ----------
// 128x128 block tile, 4 waves 2x2, wave tile 64x64 = 4x4 frags of 16x16x32 bf16, 3-term split.
// MODE 0: out = acc + bias.  MODE 2: A zeroed for rows >= U; out = relu(acc + bias).
// TBL: apply z = fmaf(x, c1[k], c0[k]) at staging.  AMAX: z = max(z, 0) (folded BN-relu).
template<int K, int F, int MODE, bool AMAX, bool TBL>
__global__ __launch_bounds__(256, 3) void k_gemm(const float* __restrict__ A,
                                                 const unsigned short* __restrict__ WH,
                                                 const unsigned short* __restrict__ WL,
                                                 const float* __restrict__ c0a, const float* __restrict__ c1a,
                                                 const float* __restrict__ bias, const int* __restrict__ devU,
                                                 float* __restrict__ out) {
    __shared__ unsigned AsH[128 * 32], AsL[128 * 32];   // 128 rows x 64 elems (u32 = 2 bf16)
    const int tid = threadIdx.x;
    const int row0 = blockIdx.y * 128;
    const int col0 = blockIdx.x * 128;
    const int w = tid >> 6, lane = tid & 63;
    const int wm = w >> 1, wn = w & 1;
    const int lr = lane & 15, lg = lane >> 4;
    const int r0 = tid >> 2, q0 = tid & 3;   // staging: rows r0, r0+64; 16-elem group q0

    int U = 0x7fffffff;
    if constexpr (MODE == 2) U = *devU;

    f32x4 acc[4][4];
    #pragma unroll
    for (int m = 0; m < 4; m++)
        #pragma unroll
        for (int n = 0; n < 4; n++) acc[m][n] = (f32x4)(0.f);

    float4 ld[2][4];
    // prefetch kc = 0
    #pragma unroll
    for (int un = 0; un < 2; ++un) {
        const float4* p4 = (const float4*)(A + (size_t)(row0 + r0 + un * 64) * K + q0 * 16);
        #pragma unroll
        for (int p = 0; p < 4; ++p) ld[un][p] = p4[p];
    }

    for (int kc = 0; kc < K; kc += 64) {
        float4 tc0[4], tc1[4];
        if constexpr (TBL) {
            #pragma unroll
            for (int p = 0; p < 4; ++p) {
                tc0[p] = *(const float4*)&c0a[kc + q0 * 16 + p * 4];
                tc1[p] = *(const float4*)&c1a[kc + q0 * 16 + p * 4];
            }
        }
        __syncthreads();   // previous MFMA phase done with LDS
        #pragma unroll
        for (int un = 0; un < 2; ++un) {
            int r = r0 + un * 64;
            unsigned swz = (unsigned)((r & 7) << 2);
            bool valid = true;
            if constexpr (MODE == 2) valid = (row0 + r) < U;
            unsigned uh[8], ul[8];
            #pragma unroll
            for (int p = 0; p < 4; ++p) {
                float zz[4] = {ld[un][p].x, ld[un][p].y, ld[un][p].z, ld[un][p].w};
                #pragma unroll
                for (int e = 0; e < 4; ++e) {
                    float z = zz[e];
                    if constexpr (MODE == 2) z = valid ? z : 0.f;
                    if constexpr (TBL) z = fmaf(z, (&tc1[p].x)[e], (&tc0[p].x)[e]);
                    if constexpr (AMAX) z = fmaxf(z, 0.f);
                    zz[e] = z;
                }
                #pragma unroll
                for (int h = 0; h < 2; ++h) {
                    unsigned u0 = __float_as_uint(zz[h * 2]), u1 = __float_as_uint(zz[h * 2 + 1]);
                    unsigned hi = (u1 & 0xFFFF0000u) | (u0 >> 16);           // trunc-hi pair
                    float l0 = zz[h * 2]     - __uint_as_float(u0 & 0xFFFF0000u);
                    float l1 = zz[h * 2 + 1] - __uint_as_float(u1 & 0xFFFF0000u);
                    unsigned lo = ((unsigned)f2bf(l1) << 16) | (unsigned)f2bf(l0); // RNE-lo pair
                    uh[p * 2 + h] = hi;
                    ul[p * 2 + h] = lo;
                }
            }
            unsigned b0 = r * 32 + ((q0 * 8 + 0) ^ swz);
            unsigned b1 = r * 32 + ((q0 * 8 + 4) ^ swz);
            *(uint4*)&AsH[b0] = make_uint4(uh[0], uh[1], uh[2], uh[3]);
            *(uint4*)&AsH[b1] = make_uint4(uh[4], uh[5], uh[6], uh[7]);
            *(uint4*)&AsL[b0] = make_uint4(ul[0], ul[1], ul[2], ul[3]);
            *(uint4*)&AsL[b1] = make_uint4(ul[4], ul[5], ul[6], ul[7]);
        }
        __syncthreads();
        // prefetch next chunk (overlaps MFMA phase)
        if (kc + 64 < K) {
            #pragma unroll
            for (int un = 0; un < 2; ++un) {
                const float4* p4 = (const float4*)(A + (size_t)(row0 + r0 + un * 64) * K + kc + 64 + q0 * 16);
                #pragma unroll
                for (int p = 0; p < 4; ++p) ld[un][p] = p4[p];
            }
        }
        #pragma unroll
        for (int kb = 0; kb < 2; ++kb) {
            short8 bh[4], bl[4];
            #pragma unroll
            for (int n = 0; n < 4; n++) {
                int c = col0 + wn * 64 + n * 16 + lr;
                size_t off = (size_t)c * K + kc + kb * 32 + lg * 8;
                bh[n] = *(const short8*)(WH + off);
                bl[n] = *(const short8*)(WL + off);
            }
            #pragma unroll
            for (int m = 0; m < 4; m++) {
                int rr = wm * 64 + m * 16 + lr;
                unsigned base = rr * 32 + ((kb * 16 + lg * 4) ^ ((unsigned)(rr & 7) << 2));
                short8 ah = *(const short8*)&AsH[base];
                short8 al = *(const short8*)&AsL[base];
                #pragma unroll
                for (int n = 0; n < 4; n++) {
                    acc[m][n] = __builtin_amdgcn_mfma_f32_16x16x32_bf16(ah, bh[n], acc[m][n], 0, 0, 0);
                    acc[m][n] = __builtin_amdgcn_mfma_f32_16x16x32_bf16(ah, bl[n], acc[m][n], 0, 0, 0);
                    acc[m][n] = __builtin_amdgcn_mfma_f32_16x16x32_bf16(al, bh[n], acc[m][n], 0, 0, 0);
                }
            }
        }
    }

    float bn[4];
    #pragma unroll
    for (int n = 0; n < 4; n++) bn[n] = bias[col0 + wn * 64 + n * 16 + lr];

    #pragma unroll
    for (int m = 0; m < 4; m++) {
        #pragma unroll
        for (int n = 0; n < 4; n++) {
            int col = col0 + wn * 64 + n * 16 + lr;
            #pragma unroll
            for (int reg = 0; reg < 4; reg++) {
                int row = row0 + wm * 64 + m * 16 + lg * 4 + reg;
                float v = acc[m][n][reg] + bn[n];
                if constexpr (MODE == 2) v = fmaxf(v, 0.f);
                out[(size_t)row * F + col] = v;
            }
        }
    }
}

// ---------- contiguous-segment masked max pool (one wave per voxel) ----------
__global__ __launch_bounds__(256) void k_pool(const float* __restrict__ h4,
                                              const int* __restrict__ ustart, const int* __restrict__ ucnt,
                                              const int* __restrict__ maskb_s, const int* __restrict__ devU,
                                              float* __restrict__ pooled) {
    int u = blockIdx.x * 4 + (threadIdx.x >> 6);
    if (u >= *devU) return;
    int lane = threadIdx.x & 63;
    int s = ustart[u], c = ucnt[u];
    float4 v = make_float4(-3.4e38f, -3.4e38f, -3.4e38f, -3.4e38f);
    for (int j = 0; j < c; ++j) {
        int row = s + j;
        if (maskb_s[row]) {
            float4 x = *(const float4*)&h4[(size_t)row * 256 + lane * 4];
            v.x = fmaxf(v.x, x.x);
            v.y = fmaxf(v.y, x.y);
            v.z = fmaxf(v.z, x.z);
            v.w = fmaxf(v.w, x.w);
        }
    }
    *(float4*)&pooled[(size_t)u * 256 + lane * 4] = v;
}

extern "C" void kernel_launch(void* const* d_in, const int* in_sizes, int n_in,
                              void* d_out, int out_size, void* d_ws, size_t ws_size,
                              hipStream_t stream) {
    const float* pt_fea = (const float*)d_in[0];
    const int*   pt_ind = (const int*)d_in[1];
    const float* bn0_g = (const float*)d_in[2];
    const float* bn0_b = (const float*)d_in[3];
    const float* w1 = (const float*)d_in[4];
    const float* b1 = (const float*)d_in[5];
    const float* bn1_g = (const float*)d_in[6];
    const float* bn1_b = (const float*)d_in[7];
    const float* w2 = (const float*)d_in[8];
    const float* b2 = (const float*)d_in[9];
    const float* bn2_g = (const float*)d_in[10];
    const float* bn2_b = (const float*)d_in[11];
    const float* w3 = (const float*)d_in[12];
    const float* b3 = (const float*)d_in[13];
    const float* bn3_g = (const float*)d_in[14];
    const float* bn3_b = (const float*)d_in[15];
    const float* w4 = (const float*)d_in[16];
    const float* b4 = (const float*)d_in[17];
    const float* wc = (const float*)d_in[18];
    const float* bc = (const float*)d_in[19];

    float* outF = (float*)d_out;
    float* coords_out = outF;
    float* feat_out = outF + (size_t)4 * N_PTS;

    char* wp = (char*)d_ws;
    auto alloc = [&](size_t bytes) {
        char* p = wp;
        wp += (bytes + 255) & ~(size_t)255;
        return p;
    };
    float* bufA = (float*)alloc((size_t)N_PTS * 256 * 4);
    float* bufB = (float*)alloc((size_t)N_PTS * 256 * 4);
    int* key     = (int*)alloc((size_t)N_PTS * 4);
    int* cnt     = (int*)alloc((size_t)N_PTS * 4);
    int* rank    = (int*)alloc((size_t)N_PTS * 4);
    int* startb  = (int*)alloc((size_t)N_PTS * 4);
    int* cursor  = (int*)alloc((size_t)N_PTS * 4);
    int* bucket  = (int*)alloc((size_t)N_PTS * 4);
    int* maskb_s = (int*)alloc((size_t)N_PTS * 4);
    int* maskb_o = (int*)alloc((size_t)N_PTS * 4);
    int* ustart  = (int*)alloc((size_t)N_PTS * 4);
    int* ucnt    = (int*)alloc((size_t)N_PTS * 4);
    int2* bsums  = (int2*)alloc(256 * sizeof(int2));
    int* devU    = (int*)alloc(256);
    int* n_masked= (int*)alloc(256);
    float* psum  = (float*)alloc((size_t)SBLOCKS * 256 * 4);
    float* psq   = (float*)alloc((size_t)SBLOCKS * 256 * 4);
    float* ss0   = (float*)alloc(2048);
    float* ss1   = (float*)alloc(2048);
    float* ss2   = (float*)alloc(2048);
    float* ss3   = (float*)alloc(2048);
    unsigned short* W2H = (unsigned short*)alloc(64 * 128 * 2);
    unsigned short* W2L = (unsigned short*)alloc(64 * 128 * 2);
    unsigned short* W3H = (unsigned short*)alloc(128 * 256 * 2);
    unsigned short* W3L = (unsigned short*)alloc(128 * 256 * 2);
    unsigned short* W4H = (unsigned short*)alloc(256 * 256 * 2);
    unsigned short* W4L = (unsigned short*)alloc(256 * 256 * 2);
    unsigned short* WCH = (unsigned short*)alloc(256 * 128 * 2);
    unsigned short* WCL = (unsigned short*)alloc(256 * 128 * 2);
    float* c02 = (float*)alloc(64 * 4);   float* c12 = (float*)alloc(64 * 4);
    float* c03 = (float*)alloc(128 * 4);  float* c13 = (float*)alloc(128 * 4);
    float* c04 = (float*)alloc(256 * 4);  float* c14 = (float*)alloc(256 * 4);
    float* c0c = (float*)alloc(256 * 4);  float* c1c = (float*)alloc(256 * 4);

    hipMemsetAsync(cnt, 0, (size_t)N_PTS * 4, stream);
    hipMemsetAsync(cursor, 0, (size_t)N_PTS * 4, stream);
    hipMemsetAsync(n_masked, 0, 4, stream);

    // FC weights have no BN dependency — prep up front
    k_wprep<256, 128><<<(256 * 128 + 255) / 256, 256, 0, stream>>>(wc, nullptr, WCH, WCL, c0c, c1c);

    // grouping
    k_keys<<<N_PTS / 256, 256, 0, stream>>>(pt_ind, key, cnt);
    k_scan1<<<N_PTS / 1024, 1024, 0, stream>>>(cnt, rank, startb, bsums);
    k_scan2<<<1, 256, 0, stream>>>(bsums, devU);
    k_scan3<<<N_PTS / 1024, 1024, 0, stream>>>(rank, startb, bsums);
    k_scatter<<<N_PTS / 256, 256, 0, stream>>>(key, startb, cursor, bucket);
    k_grouprank<<<N_PTS / 256, 256, 0, stream>>>(bucket, key, cnt, startb, maskb_s, maskb_o, n_masked);
    k_coords<<<N_PTS / 256, 256, 0, stream>>>(cnt, rank, startb, devU, coords_out, ustart, ucnt);

    // BN0 stats (original order)
    k_stats<9, 16><<<SBLOCKS, 256, 0, stream>>>(pt_fea, maskb_o, psum, psq);
    k_finalize<9><<<9, 256, 0, stream>>>(psum, psq, n_masked, bn0_g, bn0_b, ss0);

    // L1: gather to sorted order, bn0(x) @ w1 + b1 -> bufA (N x 64)
    k_mm1<<<N_PTS / 64, 256, 0, stream>>>(pt_fea, bucket, w1, b1, ss0, bufA);
    k_stats<64, 64><<<SBLOCKS, 256, 0, stream>>>(bufA, maskb_s, psum, psq);
    k_finalize<64><<<64, 256, 0, stream>>>(psum, psq, n_masked, bn1_g, bn1_b, ss1);
    k_wprep<64, 128><<<(64 * 128 + 255) / 256, 256, 0, stream>>>(w2, ss1, W2H, W2L, c02, c12);

    // L2: relu(bn1(bufA)) @ w2 + b2 -> bufB (N x 128)
    k_gemm<64, 128, 0, true, true><<<dim3(1, N_PTS / 128), 256, 0, stream>>>(
        bufA, W2H, W2L, c02, c12, b2, nullptr, bufB);
    k_stats<128, 128><<<SBLOCKS, 256, 0, stream>>>(bufB, maskb_s, psum, psq);
    k_finalize<128><<<128, 256, 0, stream>>>(psum, psq, n_masked, bn2_g, bn2_b, ss2);
    k_wprep<128, 256><<<(128 * 256 + 255) / 256, 256, 0, stream>>>(w3, ss2, W3H, W3L, c03, c13);

    // L3: relu(bn2(bufB)) @ w3 + b3 -> bufA (N x 256)
    k_gemm<128, 256, 0, true, true><<<dim3(2, N_PTS / 128), 256, 0, stream>>>(
        bufB, W3H, W3L, c03, c13, b3, nullptr, bufA);
    k_stats<256, 256><<<SBLOCKS, 256, 0, stream>>>(bufA, maskb_s, psum, psq);
    k_finalize<256><<<256, 256, 0, stream>>>(psum, psq, n_masked, bn3_g, bn3_b, ss3);
    k_wprep<256, 256><<<(256 * 256 + 255) / 256, 256, 0, stream>>>(w4, ss3, W4H, W4L, c04, c14);

    // L4: relu(bn3(bufA)) @ w4 + b4 -> bufB (N x 256), plain write
    k_gemm<256, 256, 0, true, true><<<dim3(2, N_PTS / 128), 256, 0, stream>>>(
        bufA, W4H, W4L, c04, c14, b4, nullptr, bufB);

    // segment max over contiguous sorted groups -> bufA (pooled, rows < U)
    k_pool<<<N_PTS / 4, 256, 0, stream>>>(bufB, ustart, ucnt, maskb_s, devU, bufA);

    // FC: relu(pooled @ wc + bc) -> feat_out (zero rows >= U)
    k_gemm<256, 128, 2, false, false><<<dim3(1, N_PTS / 128), 256, 0, stream>>>(
        bufA, WCH, WCL, c0c, c1c, bc, devU, feat_out);
}

// Round 7
// 925.901 us; speedup vs baseline: 2.0810x; 1.4650x over previous
//
#include <hip/hip_runtime.h>
#include <hip/hip_bf16.h>
#include <math.h>

#define N_PTS 262144
#define SBLOCKS 1024   // BN0 stats blocks

typedef short short8 __attribute__((ext_vector_type(8)));
typedef float f32x4 __attribute__((ext_vector_type(4)));

// ---------- helpers ----------
__device__ __forceinline__ unsigned short f2bf(float f) {  // RNE
    unsigned u = __float_as_uint(f);
    u = u + 0x7fff + ((u >> 16) & 1);
    return (unsigned short)(u >> 16);
}

// ---------- grouping ----------
__global__ void k_keys(const int* __restrict__ pt_ind, int* __restrict__ key, int* __restrict__ cnt) {
    int i = blockIdx.x * 256 + threadIdx.x;
    int b = pt_ind[i * 4 + 0], x = pt_ind[i * 4 + 1], y = pt_ind[i * 4 + 2], z = pt_ind[i * 4 + 3];
    int k = ((b * 64 + x) * 64 + y) * 16 + z;
    key[i] = k;
    atomicAdd(&cnt[k], 1);
}

__global__ __launch_bounds__(1024) void k_scan1(const int* __restrict__ cnt, int* __restrict__ rank,
                                                int* __restrict__ startb, int2* __restrict__ bsums) {
    __shared__ int so[1024], sc[1024];
    int t = threadIdx.x;
    int g = blockIdx.x * 1024 + t;
    int c = cnt[g];
    int o = (c > 0) ? 1 : 0;
    so[t] = o; sc[t] = c;
    __syncthreads();
    for (int off = 1; off < 1024; off <<= 1) {
        int vo = (t >= off) ? so[t - off] : 0;
        int vc = (t >= off) ? sc[t - off] : 0;
        __syncthreads();
        if (t >= off) { so[t] += vo; sc[t] += vc; }
        __syncthreads();
    }
    rank[g] = so[t] - o;
    startb[g] = sc[t] - c;
    if (t == 1023) bsums[blockIdx.x] = make_int2(so[t], sc[t]);
}

__global__ void k_scan2(int2* __restrict__ bsums, int* __restrict__ devU) {
    __shared__ int so[256], sc[256];
    int t = threadIdx.x;
    int2 v = bsums[t];
    so[t] = v.x; sc[t] = v.y;
    __syncthreads();
    for (int off = 1; off < 256; off <<= 1) {
        int vo = (t >= off) ? so[t - off] : 0;
        int vc = (t >= off) ? sc[t - off] : 0;
        __syncthreads();
        if (t >= off) { so[t] += vo; sc[t] += vc; }
        __syncthreads();
    }
    bsums[t] = make_int2(so[t] - v.x, sc[t] - v.y);
    if (t == 255) *devU = so[255];
}

__global__ __launch_bounds__(1024) void k_scan3(int* __restrict__ rank, int* __restrict__ startb,
                                                const int2* __restrict__ bsums) {
    int g = blockIdx.x * 1024 + threadIdx.x;
    int2 o = bsums[blockIdx.x];
    rank[g] += o.x;
    startb[g] += o.y;
}

__global__ void k_scatter(const int* __restrict__ key, const int* __restrict__ startb,
                          int* __restrict__ cursor, int* __restrict__ bucket) {
    int i = blockIdx.x * 256 + threadIdx.x;
    int k = key[i];
    int pos = startb[k] + atomicAdd(&cursor[k], 1);
    bucket[pos] = i;
}

__global__ void k_grouprank(const int* __restrict__ bucket, const int* __restrict__ key,
                            const int* __restrict__ cnt, const int* __restrict__ startb,
                            int* __restrict__ maskb_s, int* __restrict__ maskb_o,
                            int* __restrict__ n_masked) {
    int pos = blockIdx.x * 256 + threadIdx.x;
    int i = bucket[pos];
    int k = key[i];
    int s = startb[k];
    int c = cnt[k];
    int g = 0;
    for (int j = 0; j < c; j++) {
        int p = bucket[s + j];
        g += (p < i) ? 1 : 0;
    }
    int m = (g < 64) ? 1 : 0;
    maskb_s[pos] = m;
    maskb_o[i] = m;
    unsigned long long bal = __ballot(m);
    if ((threadIdx.x & 63) == 0) atomicAdd(n_masked, (int)__popcll(bal));
}

__global__ void k_coords(const int* __restrict__ cnt, const int* __restrict__ rank,
                         const int* __restrict__ startb, const int* __restrict__ devU,
                         float* __restrict__ out, int* __restrict__ ustart, int* __restrict__ ucnt) {
    int k = blockIdx.x * 256 + threadIdx.x;
    int U = *devU;
    if (cnt[k] > 0) {
        int r = rank[k];
        int z = k & 15;
        int t = k >> 4;
        int y = t & 63; t >>= 6;
        int x = t & 63;
        int b = t >> 6;
        out[r * 4 + 0] = (float)b;
        out[r * 4 + 1] = (float)x;
        out[r * 4 + 2] = (float)y;
        out[r * 4 + 3] = (float)z;
        ustart[r] = startb[k];
        ucnt[r] = cnt[k];
    }
    if (k >= U) {
        out[k * 4 + 0] = -1.f;
        out[k * 4 + 1] = -1.f;
        out[k * 4 + 2] = -1.f;
        out[k * 4 + 3] = -1.f;
    }
}

// ---------- BN0 stats (9 cols, over pt_fea in original order) ----------
template<int F, int FP>
__global__ __launch_bounds__(256) void k_stats(const float* __restrict__ buf, const int* __restrict__ maskb,
                                               float* __restrict__ psum, float* __restrict__ psq) {
    constexpr int RG = 256 / FP;
    int tid = threadIdx.x;
    int col = tid % FP;
    int rg = tid / FP;
    constexpr int RPB = N_PTS / SBLOCKS;
    int r0 = blockIdx.x * RPB;
    float s = 0.f, q = 0.f;
    for (int r = r0 + rg; r < r0 + RPB; r += RG) {
        float mf = (float)maskb[r];
        if (col < F) {
            float v = buf[(size_t)r * F + col];
            s += v * mf;
            q += v * v * mf;
        }
    }
    __shared__ float ls[256], lq[256];
    ls[tid] = s; lq[tid] = q;
    __syncthreads();
    for (int half = RG / 2; half > 0; half >>= 1) {
        if (rg < half) { ls[tid] += ls[tid + half * FP]; lq[tid] += lq[tid + half * FP]; }
        __syncthreads();
    }
    if (rg == 0 && col < F) {
        psum[blockIdx.x * F + col] = ls[tid];
        psq[blockIdx.x * F + col] = lq[tid];
    }
}

// reduce NB per-block partials -> scale/shift table
template<int F, int NB>
__global__ __launch_bounds__(256) void k_finalize(const float* __restrict__ psum, const float* __restrict__ psq,
                                                  const int* __restrict__ n_masked, const float* __restrict__ g,
                                                  const float* __restrict__ b, float* __restrict__ ss) {
    int j = blockIdx.x;
    int t = threadIdx.x;
    double s = 0.0, q = 0.0;
    for (int i = t; i < NB; i += 256) {
        s += (double)psum[(size_t)i * F + j];
        q += (double)psq[(size_t)i * F + j];
    }
    __shared__ double ds[256], dq[256];
    ds[t] = s; dq[t] = q;
    __syncthreads();
    for (int half = 128; half > 0; half >>= 1) {
        if (t < half) { ds[t] += ds[t + half]; dq[t] += dq[t + half]; }
        __syncthreads();
    }
    if (t == 0) {
        double n = (double)(*n_masked);
        double mean = ds[0] / n;
        double var = dq[0] / n - mean * mean;
        if (var < 0.0) var = 0.0;
        double scale = (double)g[j] / sqrt(var + 1e-5);
        ss[j * 2] = (float)scale;
        ss[j * 2 + 1] = (float)((double)b[j] - mean * scale);
    }
}

// ---------- W prep: fold |s| into W, split to bf16 hi/lo; emit per-k (c0,c1) ----------
template<int K, int F>
__global__ void k_wprep(const float* __restrict__ W, const float* __restrict__ ss,
                        unsigned short* __restrict__ WH, unsigned short* __restrict__ WL,
                        float* __restrict__ c0a, float* __restrict__ c1a) {
    int idx = blockIdx.x * 256 + threadIdx.x;
    if (idx >= K * F) return;
    int k = idx / F, f = idx % F;
    float s = 1.f, t = 0.f;
    if (ss) { s = ss[k * 2]; t = ss[k * 2 + 1]; }
    float sg = (s >= 0.f) ? 1.f : -1.f;
    float as = fabsf(s);
    float c1, c0;
    if (as < 1e-30f) { c1 = 0.f; c0 = fmaxf(t, 0.f); as = 1.f; }
    else { c1 = sg; c0 = t / as; }
    if (f == 0) { c0a[k] = c0; c1a[k] = c1; }
    float wv = as * W[(size_t)k * F + f];
    unsigned u = __float_as_uint(wv);
    unsigned hk = u & 0xFFFF0000u;
    float lo = wv - __uint_as_float(hk);
    WH[(size_t)f * K + k] = (unsigned short)(hk >> 16);
    WL[(size_t)f * K + k] = f2bf(lo);
}

// ---------- fp32 vector GEMM for L1 (K=9), gather + BN0, fused output stats ----------
__global__ __launch_bounds__(256) void k_mm1(const float* __restrict__ Af, const int* __restrict__ bucket,
                                             const float* __restrict__ W, const float* __restrict__ bias,
                                             const float* __restrict__ ss, const int* __restrict__ maskb_s,
                                             float* __restrict__ out,
                                             float* __restrict__ psum, float* __restrict__ psq) {
    constexpr int K = 9, F = 64, TM = 4, TN = 4;
    constexpr int SLOTS = F / TN;      // 16
    constexpr int RG = 256 / SLOTS;    // 16
    constexpr int MT = TM * RG;        // 64
    constexpr int STRIDE = 12;
    __shared__ float As[MT * STRIDE];
    __shared__ float msk[64];
    __shared__ float rs[4][256], rq[4][256];

    int tid = threadIdx.x;
    int row0 = blockIdx.x * MT;

    if (tid < 64) msk[tid] = (float)maskb_s[row0 + tid];
    for (int idx = tid; idx < MT * K; idx += 256) {
        int r = idx / K;
        int kk = idx % K;
        int src = bucket[row0 + r];
        float v = Af[(size_t)src * K + kk];
        v = v * ss[kk * 2] + ss[kk * 2 + 1];
        As[r * STRIDE + kk] = v;
    }
    __syncthreads();

    int slot = tid % SLOTS;
    int rg = tid / SLOTS;

    float acc[TM][TN];
    #pragma unroll
    for (int m = 0; m < TM; m++)
        #pragma unroll
        for (int i = 0; i < TN; i++) acc[m][i] = 0.f;

    #pragma unroll 3
    for (int k = 0; k < K; k++) {
        float w[TN];
        #pragma unroll
        for (int i = 0; i < TN; i++) w[i] = W[k * F + slot + i * SLOTS];
        #pragma unroll
        for (int m = 0; m < TM; m++) {
            float a = As[(rg * TM + m) * STRIDE + k];
            #pragma unroll
            for (int i = 0; i < TN; i++) acc[m][i] = fmaf(a, w[i], acc[m][i]);
        }
    }

    float s4[4] = {0.f, 0.f, 0.f, 0.f}, q4[4] = {0.f, 0.f, 0.f, 0.f};
    #pragma unroll
    for (int m = 0; m < TM; m++) {
        int r = row0 + rg * TM + m;
        float mf = msk[rg * TM + m];
        #pragma unroll
        for (int i = 0; i < TN; i++) {
            int c = slot + i * SLOTS;
            float v = acc[m][i] + bias[c];
            out[(size_t)r * F + c] = v;
            float t = mf * v;
            s4[i] += t;
            q4[i] += t * v;
        }
    }
    #pragma unroll
    for (int i = 0; i < 4; i++) { rs[i][tid] = s4[i]; rq[i][tid] = q4[i]; }
    __syncthreads();
    for (int half = 8; half > 0; half >>= 1) {
        if (rg < half) {
            #pragma unroll
            for (int i = 0; i < 4; i++) {
                rs[i][tid] += rs[i][tid + half * 16];
                rq[i][tid] += rq[i][tid + half * 16];
            }
        }
        __syncthreads();
    }
    if (rg == 0) {
        #pragma unroll
        for (int i = 0; i < 4; i++) {
            psum[(size_t)blockIdx.x * F + slot + i * 16] = rs[i][tid];
            psq[(size_t)blockIdx.x * F + slot + i * 16] = rq[i][tid];
        }
    }
}

// ---------- MFMA GEMM: full-width output, A in LDS hi/lo swizzled, W from L2 ----------
// Block: 128 rows x F cols; waves 2 x (F/64); wave tile 64x64 = 4x4 frags 16x16x32 bf16, 3-term split.
// MODE 0: out = acc + bias.  MODE 2: rows >= U zeroed (early-out for whole blocks); out = relu(acc+bias).
// TBL: z = fmaf(x, c1[k], c0[k]) at staging.  AMAX: z = max(z, 0).  STATS: per-block masked psum/psq of output.
template<int K, int F, int MODE, bool AMAX, bool TBL, bool STATS>
__global__ __launch_bounds__(2 * F) void k_gemm(const float* __restrict__ A,
                                                const unsigned short* __restrict__ WH,
                                                const unsigned short* __restrict__ WL,
                                                const float* __restrict__ c0a, const float* __restrict__ c1a,
                                                const float* __restrict__ bias, const int* __restrict__ devU,
                                                const int* __restrict__ maskb, float* __restrict__ out,
                                                float* __restrict__ psum, float* __restrict__ psq) {
    constexpr int THREADS = 2 * F;
    constexpr int RPASS = THREADS / 4;   // rows staged per pass
    constexpr int NPASS = 128 / RPASS;
    __shared__ unsigned AsH[128 * 32], AsL[128 * 32];
    __shared__ float msk[128];
    __shared__ float sps[F], spq[F];
    const int tid = threadIdx.x;
    const int row0 = blockIdx.x * 128;
    const int w = tid >> 6, lane = tid & 63;
    const int wm = w & 1, wn = w >> 1;
    const int lr = lane & 15, lg = lane >> 4;
    const int r0 = tid >> 2, q0 = tid & 3;

    int U = 0x7fffffff;
    if constexpr (MODE == 2) {
        U = *devU;
        if (row0 >= U) {   // fully-invalid block: output = relu(bias)
            for (int idx = tid; idx < 128 * F; idx += THREADS) {
                int rr = idx / F, cc = idx % F;
                out[(size_t)(row0 + rr) * F + cc] = fmaxf(bias[cc], 0.f);
            }
            return;
        }
    }

    if constexpr (STATS) { if (tid < 128) msk[tid] = (float)maskb[row0 + tid]; }

    f32x4 acc[4][4];
    #pragma unroll
    for (int m = 0; m < 4; m++)
        #pragma unroll
        for (int n = 0; n < 4; n++) acc[m][n] = (f32x4)(0.f);

    float4 ld[NPASS][4];
    #pragma unroll
    for (int un = 0; un < NPASS; ++un) {
        const float4* p4 = (const float4*)(A + (size_t)(row0 + r0 + un * RPASS) * K + q0 * 16);
        #pragma unroll
        for (int p = 0; p < 4; ++p) ld[un][p] = p4[p];
    }

    for (int kc = 0; kc < K; kc += 64) {
        float4 tc0[4], tc1[4];
        if constexpr (TBL) {
            #pragma unroll
            for (int p = 0; p < 4; ++p) {
                tc0[p] = *(const float4*)&c0a[kc + q0 * 16 + p * 4];
                tc1[p] = *(const float4*)&c1a[kc + q0 * 16 + p * 4];
            }
        }
        __syncthreads();   // previous MFMA phase done with LDS
        #pragma unroll
        for (int un = 0; un < NPASS; ++un) {
            int r = r0 + un * RPASS;
            unsigned swz = (unsigned)((r & 7) << 2);
            bool valid = true;
            if constexpr (MODE == 2) valid = (row0 + r) < U;
            unsigned uh[8], ul[8];
            #pragma unroll
            for (int p = 0; p < 4; ++p) {
                float zz[4] = {ld[un][p].x, ld[un][p].y, ld[un][p].z, ld[un][p].w};
                #pragma unroll
                for (int e = 0; e < 4; ++e) {
                    float z = zz[e];
                    if constexpr (MODE == 2) z = valid ? z : 0.f;
                    if constexpr (TBL) z = fmaf(z, (&tc1[p].x)[e], (&tc0[p].x)[e]);
                    if constexpr (AMAX) z = fmaxf(z, 0.f);
                    zz[e] = z;
                }
                #pragma unroll
                for (int h = 0; h < 2; ++h) {
                    unsigned u0 = __float_as_uint(zz[h * 2]), u1 = __float_as_uint(zz[h * 2 + 1]);
                    unsigned hi = (u1 & 0xFFFF0000u) | (u0 >> 16);
                    float l0 = zz[h * 2]     - __uint_as_float(u0 & 0xFFFF0000u);
                    float l1 = zz[h * 2 + 1] - __uint_as_float(u1 & 0xFFFF0000u);
                    unsigned lo = ((unsigned)f2bf(l1) << 16) | (unsigned)f2bf(l0);
                    uh[p * 2 + h] = hi;
                    ul[p * 2 + h] = lo;
                }
            }
            unsigned b0 = r * 32 + ((q0 * 8 + 0) ^ swz);
            unsigned b1 = r * 32 + ((q0 * 8 + 4) ^ swz);
            *(uint4*)&AsH[b0] = make_uint4(uh[0], uh[1], uh[2], uh[3]);
            *(uint4*)&AsH[b1] = make_uint4(uh[4], uh[5], uh[6], uh[7]);
            *(uint4*)&AsL[b0] = make_uint4(ul[0], ul[1], ul[2], ul[3]);
            *(uint4*)&AsL[b1] = make_uint4(ul[4], ul[5], ul[6], ul[7]);
        }
        __syncthreads();
        if (kc + 64 < K) {
            #pragma unroll
            for (int un = 0; un < NPASS; ++un) {
                const float4* p4 = (const float4*)(A + (size_t)(row0 + r0 + un * RPASS) * K + kc + 64 + q0 * 16);
                #pragma unroll
                for (int p = 0; p < 4; ++p) ld[un][p] = p4[p];
            }
        }
        #pragma unroll
        for (int kb = 0; kb < 2; ++kb) {
            short8 bh[4], bl[4];
            #pragma unroll
            for (int n = 0; n < 4; n++) {
                int c = wn * 64 + n * 16 + lr;
                size_t off = (size_t)c * K + kc + kb * 32 + lg * 8;
                bh[n] = *(const short8*)(WH + off);
                bl[n] = *(const short8*)(WL + off);
            }
            #pragma unroll
            for (int m = 0; m < 4; m++) {
                int rr = wm * 64 + m * 16 + lr;
                unsigned base = rr * 32 + ((kb * 16 + lg * 4) ^ ((unsigned)(rr & 7) << 2));
                short8 ah = *(const short8*)&AsH[base];
                short8 al = *(const short8*)&AsL[base];
                #pragma unroll
                for (int n = 0; n < 4; n++) {
                    acc[m][n] = __builtin_amdgcn_mfma_f32_16x16x32_bf16(ah, bh[n], acc[m][n], 0, 0, 0);
                    acc[m][n] = __builtin_amdgcn_mfma_f32_16x16x32_bf16(ah, bl[n], acc[m][n], 0, 0, 0);
                    acc[m][n] = __builtin_amdgcn_mfma_f32_16x16x32_bf16(al, bh[n], acc[m][n], 0, 0, 0);
                }
            }
        }
    }

    float bn[4];
    #pragma unroll
    for (int n = 0; n < 4; n++) bn[n] = bias[wn * 64 + n * 16 + lr];

    float s4[4] = {0.f, 0.f, 0.f, 0.f}, q4[4] = {0.f, 0.f, 0.f, 0.f};
    #pragma unroll
    for (int m = 0; m < 4; m++) {
        float mf[4];
        if constexpr (STATS) {
            #pragma unroll
            for (int reg = 0; reg < 4; reg++) mf[reg] = msk[wm * 64 + m * 16 + lg * 4 + reg];
        }
        #pragma unroll
        for (int n = 0; n < 4; n++) {
            int col = wn * 64 + n * 16 + lr;
            #pragma unroll
            for (int reg = 0; reg < 4; reg++) {
                int row = row0 + wm * 64 + m * 16 + lg * 4 + reg;
                float v = acc[m][n][reg] + bn[n];
                if constexpr (MODE == 2) v = fmaxf(v, 0.f);
                out[(size_t)row * F + col] = v;
                if constexpr (STATS) { float t = mf[reg] * v; s4[n] += t; q4[n] += t * v; }
            }
        }
    }

    if constexpr (STATS) {
        #pragma unroll
        for (int n = 0; n < 4; n++) {
            s4[n] += __shfl_xor(s4[n], 16); s4[n] += __shfl_xor(s4[n], 32);
            q4[n] += __shfl_xor(q4[n], 16); q4[n] += __shfl_xor(q4[n], 32);
        }
        if (wm == 0 && lg == 0) {
            #pragma unroll
            for (int n = 0; n < 4; n++) {
                int col = wn * 64 + n * 16 + lr;
                sps[col] = s4[n]; spq[col] = q4[n];
            }
        }
        __syncthreads();
        if (wm == 1 && lg == 0) {
            #pragma unroll
            for (int n = 0; n < 4; n++) {
                int col = wn * 64 + n * 16 + lr;
                psum[(size_t)blockIdx.x * F + col] = sps[col] + s4[n];
                psq[(size_t)blockIdx.x * F + col] = spq[col] + q4[n];
            }
        }
    }
}

// ---------- contiguous-segment masked max pool (one wave per voxel) ----------
__global__ __launch_bounds__(256) void k_pool(const float* __restrict__ h4,
                                              const int* __restrict__ ustart, const int* __restrict__ ucnt,
                                              const int* __restrict__ maskb_s, const int* __restrict__ devU,
                                              float* __restrict__ pooled) {
    int u = blockIdx.x * 4 + (threadIdx.x >> 6);
    if (u >= *devU) return;
    int lane = threadIdx.x & 63;
    int s = ustart[u], c = ucnt[u];
    float4 v = make_float4(-3.4e38f, -3.4e38f, -3.4e38f, -3.4e38f);
    for (int j = 0; j < c; ++j) {
        int row = s + j;
        if (maskb_s[row]) {
            float4 x = *(const float4*)&h4[(size_t)row * 256 + lane * 4];
            v.x = fmaxf(v.x, x.x);
            v.y = fmaxf(v.y, x.y);
            v.z = fmaxf(v.z, x.z);
            v.w = fmaxf(v.w, x.w);
        }
    }
    *(float4*)&pooled[(size_t)u * 256 + lane * 4] = v;
}

extern "C" void kernel_launch(void* const* d_in, const int* in_sizes, int n_in,
                              void* d_out, int out_size, void* d_ws, size_t ws_size,
                              hipStream_t stream) {
    const float* pt_fea = (const float*)d_in[0];
    const int*   pt_ind = (const int*)d_in[1];
    const float* bn0_g = (const float*)d_in[2];
    const float* bn0_b = (const float*)d_in[3];
    const float* w1 = (const float*)d_in[4];
    const float* b1 = (const float*)d_in[5];
    const float* bn1_g = (const float*)d_in[6];
    const float* bn1_b = (const float*)d_in[7];
    const float* w2 = (const float*)d_in[8];
    const float* b2 = (const float*)d_in[9];
    const float* bn2_g = (const float*)d_in[10];
    const float* bn2_b = (const float*)d_in[11];
    const float* w3 = (const float*)d_in[12];
    const float* b3 = (const float*)d_in[13];
    const float* bn3_g = (const float*)d_in[14];
    const float* bn3_b = (const float*)d_in[15];
    const float* w4 = (const float*)d_in[16];
    const float* b4 = (const float*)d_in[17];
    const float* wc = (const float*)d_in[18];
    const float* bc = (const float*)d_in[19];

    float* outF = (float*)d_out;
    float* coords_out = outF;
    float* feat_out = outF + (size_t)4 * N_PTS;

    char* wp = (char*)d_ws;
    auto alloc = [&](size_t bytes) {
        char* p = wp;
        wp += (bytes + 255) & ~(size_t)255;
        return p;
    };
    float* bufA = (float*)alloc((size_t)N_PTS * 256 * 4);
    float* bufB = (float*)alloc((size_t)N_PTS * 256 * 4);
    int* key     = (int*)alloc((size_t)N_PTS * 4);
    int* cnt     = (int*)alloc((size_t)N_PTS * 4);
    int* rank    = (int*)alloc((size_t)N_PTS * 4);
    int* startb  = (int*)alloc((size_t)N_PTS * 4);
    int* cursor  = (int*)alloc((size_t)N_PTS * 4);
    int* bucket  = (int*)alloc((size_t)N_PTS * 4);
    int* maskb_s = (int*)alloc((size_t)N_PTS * 4);
    int* maskb_o = (int*)alloc((size_t)N_PTS * 4);
    int* ustart  = (int*)alloc((size_t)N_PTS * 4);
    int* ucnt    = (int*)alloc((size_t)N_PTS * 4);
    int2* bsums  = (int2*)alloc(256 * sizeof(int2));
    int* devU    = (int*)alloc(256);
    int* n_masked= (int*)alloc(256);
    float* psum  = (float*)alloc((size_t)2048 * 256 * 4);
    float* psq   = (float*)alloc((size_t)2048 * 256 * 4);
    float* ss0   = (float*)alloc(2048);
    float* ss1   = (float*)alloc(2048);
    float* ss2   = (float*)alloc(2048);
    float* ss3   = (float*)alloc(2048);
    unsigned short* W2H = (unsigned short*)alloc(64 * 128 * 2);
    unsigned short* W2L = (unsigned short*)alloc(64 * 128 * 2);
    unsigned short* W3H = (unsigned short*)alloc(128 * 256 * 2);
    unsigned short* W3L = (unsigned short*)alloc(128 * 256 * 2);
    unsigned short* W4H = (unsigned short*)alloc(256 * 256 * 2);
    unsigned short* W4L = (unsigned short*)alloc(256 * 256 * 2);
    unsigned short* WCH = (unsigned short*)alloc(256 * 128 * 2);
    unsigned short* WCL = (unsigned short*)alloc(256 * 128 * 2);
    float* c02 = (float*)alloc(64 * 4);   float* c12 = (float*)alloc(64 * 4);
    float* c03 = (float*)alloc(128 * 4);  float* c13 = (float*)alloc(128 * 4);
    float* c04 = (float*)alloc(256 * 4);  float* c14 = (float*)alloc(256 * 4);
    float* c0c = (float*)alloc(256 * 4);  float* c1c = (float*)alloc(256 * 4);

    hipMemsetAsync(cnt, 0, (size_t)N_PTS * 4, stream);
    hipMemsetAsync(cursor, 0, (size_t)N_PTS * 4, stream);
    hipMemsetAsync(n_masked, 0, 4, stream);

    // FC weights have no BN dependency — prep up front
    k_wprep<256, 128><<<(256 * 128 + 255) / 256, 256, 0, stream>>>(wc, nullptr, WCH, WCL, c0c, c1c);

    // grouping
    k_keys<<<N_PTS / 256, 256, 0, stream>>>(pt_ind, key, cnt);
    k_scan1<<<N_PTS / 1024, 1024, 0, stream>>>(cnt, rank, startb, bsums);
    k_scan2<<<1, 256, 0, stream>>>(bsums, devU);
    k_scan3<<<N_PTS / 1024, 1024, 0, stream>>>(rank, startb, bsums);
    k_scatter<<<N_PTS / 256, 256, 0, stream>>>(key, startb, cursor, bucket);
    k_grouprank<<<N_PTS / 256, 256, 0, stream>>>(bucket, key, cnt, startb, maskb_s, maskb_o, n_masked);
    k_coords<<<N_PTS / 256, 256, 0, stream>>>(cnt, rank, startb, devU, coords_out, ustart, ucnt);

    // BN0 stats (original order)
    k_stats<9, 16><<<SBLOCKS, 256, 0, stream>>>(pt_fea, maskb_o, psum, psq);
    k_finalize<9, SBLOCKS><<<9, 256, 0, stream>>>(psum, psq, n_masked, bn0_g, bn0_b, ss0);

    // L1: gather, bn0(x) @ w1 + b1 -> bufA (N x 64); fused stats
    k_mm1<<<N_PTS / 64, 256, 0, stream>>>(pt_fea, bucket, w1, b1, ss0, maskb_s, bufA, psum, psq);
    k_finalize<64, N_PTS / 64><<<64, 256, 0, stream>>>(psum, psq, n_masked, bn1_g, bn1_b, ss1);
    k_wprep<64, 128><<<(64 * 128 + 255) / 256, 256, 0, stream>>>(w2, ss1, W2H, W2L, c02, c12);

    // L2: relu(bn1(bufA)) @ w2 + b2 -> bufB (N x 128); fused stats
    k_gemm<64, 128, 0, true, true, true><<<N_PTS / 128, 256, 0, stream>>>(
        bufA, W2H, W2L, c02, c12, b2, nullptr, maskb_s, bufB, psum, psq);
    k_finalize<128, N_PTS / 128><<<128, 256, 0, stream>>>(psum, psq, n_masked, bn2_g, bn2_b, ss2);
    k_wprep<128, 256><<<(128 * 256 + 255) / 256, 256, 0, stream>>>(w3, ss2, W3H, W3L, c03, c13);

    // L3: relu(bn2(bufB)) @ w3 + b3 -> bufA (N x 256); fused stats
    k_gemm<128, 256, 0, true, true, true><<<N_PTS / 128, 512, 0, stream>>>(
        bufB, W3H, W3L, c03, c13, b3, nullptr, maskb_s, bufA, psum, psq);
    k_finalize<256, N_PTS / 128><<<256, 256, 0, stream>>>(psum, psq, n_masked, bn3_g, bn3_b, ss3);
    k_wprep<256, 256><<<(256 * 256 + 255) / 256, 256, 0, stream>>>(w4, ss3, W4H, W4L, c04, c14);

    // L4: relu(bn3(bufA)) @ w4 + b4 -> bufB (N x 256)
    k_gemm<256, 256, 0, true, true, false><<<N_PTS / 128, 512, 0, stream>>>(
        bufA, W4H, W4L, c04, c14, b4, nullptr, nullptr, bufB, nullptr, nullptr);

    // segment max over contiguous sorted groups -> bufA (pooled, rows < U)
    k_pool<<<N_PTS / 4, 256, 0, stream>>>(bufB, ustart, ucnt, maskb_s, devU, bufA);

    // FC: relu(pooled @ wc + bc) -> feat_out (early-out + zero rows >= U)
    k_gemm<256, 128, 2, false, false, false><<<N_PTS / 128, 256, 0, stream>>>(
        bufA, WCH, WCL, nullptr, nullptr, bc, devU, nullptr, feat_out, nullptr, nullptr);
}